// Round 23
// baseline (194.155 us; speedup 1.0000x reference)
//
#include <hip/hip_runtime.h>
#include <hip/hip_fp16.h>

// PointSetDifferenceModule: B=4, N=8192, C=64, K=16
// Round 23: diff_out_k v2 — LDS-free/barrier-free (yfin-v3 recipe): W2 prepacked
// bf16 in global (L2), h-row fragments built in registers from gathered gd,
// max-over-K via shfl_xor on the D fragment. Rest = round 22 (161us, 0.03125).
// FT row (384B): [ f fp16 x64 | G_d bf16 x64 | G_s bf16 x64 ]

#define Bn 4
#define Nn 8192
#define NPTS (Bn * Nn)        // 32768
#define NSAMP (NPTS * 16)     // 524288
#define EPSf 1e-5f
#define FT_STRIDE 384
#define FTSZ ((size_t)NPTS * FT_STRIDE + 1024)
#define GSZ (NPTS * 64)

typedef __attribute__((ext_vector_type(8))) short v8bf;
typedef __attribute__((ext_vector_type(4))) float v4f;
typedef __attribute__((ext_vector_type(2))) _Float16 v2h;

union U2H {
  unsigned u;
  v2h h;
};

__device__ inline unsigned pack_bf16x2(float a, float b) {
  unsigned ua = __float_as_uint(a), ub = __float_as_uint(b);
  ua = (ua + 0x7FFFu + ((ua >> 16) & 1u)) >> 16;
  ub = (ub + 0x7FFFu + ((ub >> 16) & 1u)) >> 16;
  return (ub << 16) | ua;
}
__device__ inline float bf16_lo(unsigned u) { return __uint_as_float(u << 16); }
__device__ inline float bf16_hi(unsigned u) { return __uint_as_float(u & 0xFFFF0000u); }

__device__ inline float dot2acc(unsigned a, unsigned b, float c) {
  U2H ua, ub;
  ua.u = a;
  ub.u = b;
#if __has_builtin(__builtin_amdgcn_fdot2)
  return __builtin_amdgcn_fdot2(ua.h, ub.h, c, false);
#else
  return c + (float)ua.h.x * (float)ub.h.x + (float)ua.h.y * (float)ub.h.y;
#endif
}

// ---------------- W' = fw1[:,64:128] @ sw2  (128x64, fp32) ----------------
__global__ void wprep(const float* __restrict__ fw1, const float* __restrict__ sw2,
                      float* __restrict__ Wp) {
  int gid = blockIdx.x * 256 + threadIdx.x;  // 8192
  int j = gid >> 6, k = gid & 63;
  float s = 0.f;
#pragma unroll 8
  for (int c = 0; c < 64; c++) s += fw1[j * 128 + 64 + c] * sw2[c * 64 + k];
  Wp[gid] = s;
}

// ---------------- Wcomb[j][u] = pack_bf16( [fw1L | Wp][j][2u..2u+1] ) ------------
__global__ void wpack(const float* __restrict__ fw1, const float* __restrict__ Wp,
                      unsigned* __restrict__ Wcomb) {
  int gid = blockIdx.x * 256 + threadIdx.x;  // 8192
  int j = gid >> 6, u = gid & 63;
  int c = u * 2;
  float a, b;
  if (c < 64) {
    a = fw1[j * 128 + c];
    b = fw1[j * 128 + c + 1];
  } else {
    a = Wp[j * 64 + (c - 64)];
    b = Wp[j * 64 + (c - 64) + 1];
  }
  Wcomb[gid] = pack_bf16x2(a, b);
}

// ---------------- Wc2[j][u] = pack_bf16(w2d[j][2u..2u+1])  (64x32 u32) -----------
__global__ void w2pack(const float* __restrict__ w2d, unsigned* __restrict__ Wc2) {
  int gid = blockIdx.x * 256 + threadIdx.x;  // 2048
  int j = gid >> 5, u = gid & 31;
  Wc2[gid] = pack_bf16x2(w2d[j * 64 + u * 2], w2d[j * 64 + u * 2 + 1]);
}

// ---------------- build fused tables: f fp16 + G_d, G_s bf16 ----------------
__global__ __launch_bounds__(256) void gemmG(const float* __restrict__ f0,
                                             const float* __restrict__ f1,
                                             const float* __restrict__ wd,
                                             const float* __restrict__ wsim,
                                             char* __restrict__ FT0,
                                             char* __restrict__ FT1) {
  int z = blockIdx.z;
  const float* F = z ? f1 : f0;
  char* FT = z ? FT1 : FT0;
  __shared__ float Fl[64][65];
  __shared__ float Wd[64][65];
  __shared__ float Ws[64][65];
  int t = threadIdx.x;
#pragma unroll
  for (int i = 0; i < 16; i++) {
    int ix = t + i * 256;
    Wd[ix >> 6][ix & 63] = wd[ix];
    Ws[ix >> 6][ix & 63] = wsim[ix];
  }
  int ptb = blockIdx.x * 64;
#pragma unroll
  for (int i = 0; i < 8; i++) {
    int pr = t + i * 256;  // pair index 0..2047
    int row = pr >> 5, c2 = pr & 31;
    float2 v = *(const float2*)(F + (size_t)(ptb + row) * 64 + c2 * 2);
    Fl[row][c2 * 2] = v.x;
    Fl[row][c2 * 2 + 1] = v.y;
    __half2 h2 = __floats2half2_rn(v.x, v.y);
    *(unsigned*)(FT + (size_t)(ptb + row) * FT_STRIDE + c2 * 4) =
        *reinterpret_cast<unsigned*>(&h2);
  }
  __syncthreads();
  int ty = t >> 4, tx = t & 15, r0 = ty * 4, c0 = tx * 4;
  float ad[4][4] = {}, as_[4][4] = {};
#pragma unroll 4
  for (int j = 0; j < 64; ++j) {
    float a[4], w1[4], w2[4];
#pragma unroll
    for (int i = 0; i < 4; i++) a[i] = Fl[r0 + i][j];
#pragma unroll
    for (int m = 0; m < 4; m++) {
      w1[m] = Wd[c0 + m][j];
      w2[m] = Ws[c0 + m][j];
    }
#pragma unroll
    for (int i = 0; i < 4; i++)
#pragma unroll
      for (int m = 0; m < 4; m++) {
        ad[i][m] += a[i] * w1[m];
        as_[i][m] += a[i] * w2[m];
      }
  }
#pragma unroll
  for (int i = 0; i < 4; i++) {
    char* row = FT + (size_t)(ptb + r0 + i) * FT_STRIDE;
    uint2 gd2 = make_uint2(pack_bf16x2(ad[i][0], ad[i][1]),
                           pack_bf16x2(ad[i][2], ad[i][3]));
    *(uint2*)(row + 128 + c0 * 2) = gd2;
    uint2 gs2 = make_uint2(pack_bf16x2(as_[i][0], as_[i][1]),
                           pack_bf16x2(as_[i][2], as_[i][3]));
    *(uint2*)(row + 256 + c0 * 2) = gs2;
  }
}

// ---------------- diff stats + sim softmax + y_sim (8 points per wave) ----------
__global__ __launch_bounds__(256) void stats_sim(
    const char* __restrict__ FT0, const char* __restrict__ FT1,
    const int* __restrict__ i01, const int* __restrict__ i10,
    float* __restrict__ YS0, float* __restrict__ YS1, float* __restrict__ acc) {
  int u = blockIdx.x & 7;
  int dir = u & 1, batch = u >> 1;
  const char* FS = dir ? FT1 : FT0;
  const char* FO = dir ? FT0 : FT1;
  const int* idx = dir ? i10 : i01;
  float* ys = dir ? YS1 : YS0;
  float* accDiff = acc + dir * 128;
  float* accSim = acc + 256 + dir * 128;
  int lane = threadIdx.x & 63, wave = threadIdx.x >> 6;
  int s = lane & 7, g = lane >> 3;
  int ptbase = batch * Nn + (blockIdx.x >> 3) * 32 + wave * 8;
  int bbase = batch * Nn;
  int myidx0 = idx[ptbase * 16 + lane];
  int myidx1 = idx[ptbase * 16 + 64 + lane];
  const char* srow = FS + (size_t)(ptbase + g) * FT_STRIDE;
  uint4 fs4 = *(const uint4*)(srow + s * 16);
  uint4 gds4 = *(const uint4*)(srow + 128 + s * 16);
  float gds[8] = {bf16_lo(gds4.x), bf16_hi(gds4.x), bf16_lo(gds4.y), bf16_hi(gds4.y),
                  bf16_lo(gds4.z), bf16_hi(gds4.z), bf16_lo(gds4.w), bf16_hi(gds4.w)};
  const char* ob = FO + (size_t)bbase * FT_STRIDE;
  int gq = (g & 3) * 16;
  bool hi = g >= 4;
  float S1[8] = {0, 0, 0, 0, 0, 0, 0, 0};
  float S2[8] = {0, 0, 0, 0, 0, 0, 0, 0};
  float ya[8] = {0, 0, 0, 0, 0, 0, 0, 0};
  float den = 0.f;
#pragma unroll 1
  for (int kc = 0; kc < 16; kc += 4) {
    uint4 fo[4], gdo[4], gso[4];
#pragma unroll
    for (int k = 0; k < 4; k++) {
      int jA = __shfl(myidx0, gq + kc + k);
      int jB = __shfl(myidx1, gq + kc + k);
      int j = hi ? jB : jA;
      const char* orow = ob + (size_t)j * FT_STRIDE;
      fo[k] = *(const uint4*)(orow + s * 16);
      gdo[k] = *(const uint4*)(orow + 128 + s * 16);
      gso[k] = *(const uint4*)(orow + 256 + s * 16);
    }
    float sims[4];
#pragma unroll
    for (int k = 0; k < 4; k++) {
      float p = dot2acc(fs4.x, fo[k].x, 0.f);
      p = dot2acc(fs4.y, fo[k].y, p);
      p = dot2acc(fs4.z, fo[k].z, p);
      p = dot2acc(fs4.w, fo[k].w, p);
      p += __shfl_xor(p, 4);
      p += __shfl_xor(p, 2);
      p += __shfl_xor(p, 1);
      sims[k] = p;
      float t0 = bf16_lo(gdo[k].x), t1 = bf16_hi(gdo[k].x);
      float t2 = bf16_lo(gdo[k].y), t3 = bf16_hi(gdo[k].y);
      float t4 = bf16_lo(gdo[k].z), t5 = bf16_hi(gdo[k].z);
      float t6 = bf16_lo(gdo[k].w), t7 = bf16_hi(gdo[k].w);
      S1[0] += t0; S2[0] += t0 * t0;
      S1[1] += t1; S2[1] += t1 * t1;
      S1[2] += t2; S2[2] += t2 * t2;
      S1[3] += t3; S2[3] += t3 * t3;
      S1[4] += t4; S2[4] += t4 * t4;
      S1[5] += t5; S2[5] += t5 * t5;
      S1[6] += t6; S2[6] += t6 * t6;
      S1[7] += t7; S2[7] += t7 * t7;
    }
#pragma unroll
    for (int k = 0; k < 4; k++) {
      float e = __expf(sims[k]);
      den += e;
      ya[0] += e * bf16_lo(gso[k].x);
      ya[1] += e * bf16_hi(gso[k].x);
      ya[2] += e * bf16_lo(gso[k].y);
      ya[3] += e * bf16_hi(gso[k].y);
      ya[4] += e * bf16_lo(gso[k].z);
      ya[5] += e * bf16_hi(gso[k].z);
      ya[6] += e * bf16_lo(gso[k].w);
      ya[7] += e * bf16_hi(gso[k].w);
    }
  }
  float inv = 1.f / den;
#pragma unroll
  for (int i = 0; i < 8; i++) ya[i] *= inv;
  float* yrow = ys + (size_t)(ptbase + g) * 64 + s * 8;
  *(float4*)(yrow) = make_float4(ya[0], ya[1], ya[2], ya[3]);
  *(float4*)(yrow + 4) = make_float4(ya[4], ya[5], ya[6], ya[7]);
  float sd[8], qd[8], qs[8];
#pragma unroll
  for (int i = 0; i < 8; i++) {
    sd[i] = 16.f * gds[i] - S1[i];
    qd[i] = 16.f * gds[i] * gds[i] - 2.f * gds[i] * S1[i] + S2[i];
    qs[i] = ya[i] * ya[i];
  }
#define GRED(x)           \
  x += __shfl_xor(x, 8);  \
  x += __shfl_xor(x, 16); \
  x += __shfl_xor(x, 32);
#pragma unroll
  for (int i = 0; i < 8; i++) {
    GRED(sd[i]) GRED(qd[i]) GRED(ya[i]) GRED(qs[i])
  }
#undef GRED
  __shared__ float red[4][4][64];
  if (lane < 8) {
#pragma unroll
    for (int i = 0; i < 8; i++) {
      red[wave][0][s * 8 + i] = sd[i];
      red[wave][1][s * 8 + i] = qd[i];
      red[wave][2][s * 8 + i] = ya[i];
      red[wave][3][s * 8 + i] = qs[i];
    }
  }
  __syncthreads();
  if (wave == 0) {
    float v = red[0][0][lane] + red[1][0][lane] + red[2][0][lane] + red[3][0][lane];
    atomicAdd(accDiff + lane, v);
    v = red[0][1][lane] + red[1][1][lane] + red[2][1][lane] + red[3][1][lane];
    atomicAdd(accDiff + 64 + lane, v);
    v = red[0][2][lane] + red[1][2][lane] + red[2][2][lane] + red[3][2][lane];
    atomicAdd(accSim + lane, v);
    v = red[0][3][lane] + red[1][3][lane] + red[2][3][lane] + red[3][3][lane];
    atomicAdd(accSim + 64 + lane, v);
  }
}

// ---- diff output v2: LDS-free. A=W2(bf16,L2), B=h rows in regs; max-K via shfl ----
// wave owns point p; lane (lr,lg): B-col k=lr, channels kk*32+lg*8..+7.
__global__ __launch_bounds__(256) void diff_out_k(
    const char* __restrict__ FT0, const char* __restrict__ FT1,
    const int* __restrict__ i01, const int* __restrict__ i10,
    const unsigned* __restrict__ Wc2, const float* __restrict__ b2d,
    const float* __restrict__ acc, const float* __restrict__ dg,
    const float* __restrict__ dbe, float* __restrict__ DF0, float* __restrict__ DF1) {
  int u = blockIdx.x & 7;
  int dir = u & 1, batch = u >> 1;
  const char* FS = dir ? FT1 : FT0;
  const char* FO = dir ? FT0 : FT1;
  const int* idx = dir ? i10 : i01;
  const float* aD = acc + dir * 128;
  float* dout = dir ? DF1 : DF0;
  int t = threadIdx.x;
  int wave = t >> 6, lane = t & 63, lr = lane & 15, lg = lane >> 4;
  // per-lane BN consts for channels kk*32 + lg*8 + i
  float sc[2][8], sh[2][8];
#pragma unroll
  for (int kk = 0; kk < 2; kk++)
#pragma unroll
    for (int i = 0; i < 8; i++) {
      int ch = kk * 32 + lg * 8 + i;
      float mu = aD[ch] / (float)NSAMP;
      float var = aD[64 + ch] / (float)NSAMP - mu * mu;
      float s = dg[ch] * rsqrtf(var + EPSf);
      sc[kk][i] = s;
      sh[kk][i] = dbe[ch] - mu * s;
    }
  // W2 fragments: row jb*16+lr, u32 offset kk*16+lg*4 (row stride 32 u32)
  v8bf wf[4][2];
#pragma unroll
  for (int jb = 0; jb < 4; jb++)
#pragma unroll
    for (int kk = 0; kk < 2; kk++)
      wf[jb][kk] =
          *(const v8bf*)(Wc2 + (size_t)(jb * 16 + lr) * 32 + kk * 16 + lg * 4);
  float4 bb4[4];
#pragma unroll
  for (int jb = 0; jb < 4; jb++) bb4[jb] = *(const float4*)(b2d + jb * 16 + lg * 4);
  int wblk = blockIdx.x >> 3;
  int bbase = batch * Nn;
#pragma unroll 1
  for (int tt = 0; tt < 4; tt++) {
    int p = bbase + (wblk * 4 + tt) * 4 + wave;
    int nbr = idx[p * 16 + lr];
    const char* srow = FS + (size_t)p * FT_STRIDE + 128;
    const char* orow = FO + (size_t)(bbase + nbr) * FT_STRIDE + 128;
    v8bf pb[2];
#pragma unroll
    for (int kk = 0; kk < 2; kk++) {
      uint4 gs4 = *(const uint4*)(srow + kk * 64 + lg * 16);
      uint4 go4 = *(const uint4*)(orow + kk * 64 + lg * 16);
      const unsigned* gsp = (const unsigned*)&gs4;
      const unsigned* gop = (const unsigned*)&go4;
      unsigned hu[4];
#pragma unroll
      for (int w2 = 0; w2 < 4; w2++) {
        float y0 = bf16_lo(gsp[w2]) - bf16_lo(gop[w2]);
        float y1 = bf16_hi(gsp[w2]) - bf16_hi(gop[w2]);
        float h0 = fmaxf(sc[kk][w2 * 2] * y0 + sh[kk][w2 * 2], 0.f);
        float h1 = fmaxf(sc[kk][w2 * 2 + 1] * y1 + sh[kk][w2 * 2 + 1], 0.f);
        hu[w2] = pack_bf16x2(h0, h1);
      }
      pb[kk] = *(const v8bf*)hu;
    }
    v4f a4[4] = {{0, 0, 0, 0}, {0, 0, 0, 0}, {0, 0, 0, 0}, {0, 0, 0, 0}};
#pragma unroll
    for (int jb = 0; jb < 4; jb++)
#pragma unroll
      for (int kk = 0; kk < 2; kk++)
        a4[jb] =
            __builtin_amdgcn_mfma_f32_16x16x32_bf16(wf[jb][kk], pb[kk], a4[jb], 0, 0, 0);
    // max over k = lr lanes (D col = k); rows j = jb*16 + lg*4 + i
#pragma unroll
    for (int jb = 0; jb < 4; jb++) {
#pragma unroll
      for (int i = 0; i < 4; i++) {
        float m = a4[jb][i];
        m = fmaxf(m, __shfl_xor(m, 1));
        m = fmaxf(m, __shfl_xor(m, 2));
        m = fmaxf(m, __shfl_xor(m, 4));
        m = fmaxf(m, __shfl_xor(m, 8));
        a4[jb][i] = m;
      }
      if (lr == 0) {
        float4 o = make_float4(a4[jb][0] + bb4[jb].x, a4[jb][1] + bb4[jb].y,
                               a4[jb][2] + bb4[jb].z, a4[jb][3] + bb4[jb].w);
        *(float4*)(dout + (size_t)p * 64 + jb * 16 + lg * 4) = o;
      }
    }
  }
}

// ---- YF(bf16) = [DF | relu_bn(YS)] @ [fw1L | W']^T + fin BN stats (LDS-free) ----
__global__ __launch_bounds__(256) void yfin_gemm(
    const float* __restrict__ DF0, const float* __restrict__ DF1,
    const float* __restrict__ YS0, const float* __restrict__ YS1,
    const unsigned* __restrict__ Wcomb, const float* __restrict__ sg,
    const float* __restrict__ sbe, unsigned* __restrict__ YF0b,
    unsigned* __restrict__ YF1b, float* __restrict__ acc) {
  int dir = blockIdx.y;
  const float* df = dir ? DF1 : DF0;
  const float* ysim = dir ? YS1 : YS0;
  unsigned* yfb = dir ? YF1b : YF0b;
  const float* aS = acc + 256 + dir * 128;
  float* accF = acc + 512 + dir * 256;
  __shared__ float redS[4][128], redQ[4][128];
  __shared__ float scs[64], shs[64];
  int t = threadIdx.x;
  int ptb = blockIdx.x * 64;
  if (t < 64) {
    float mu = aS[t] / (float)NPTS;
    float var = aS[64 + t] / (float)NPTS - mu * mu;
    float scale = sg[t] * rsqrtf(var + EPSf);
    scs[t] = scale;
    shs[t] = sbe[t] - mu * scale;
  }
  __syncthreads();
  int wave = t >> 6, lane = t & 63, lr = lane & 15, lg = lane >> 4;
  int ptB = ptb + wave * 16 + lr;
  v8bf pb[4];
#pragma unroll
  for (int kk = 0; kk < 4; kk++) {
    int ch = kk * 32 + lg * 8;
    float4 v0, v1;
    if (ch < 64) {
      v0 = *(const float4*)(df + (size_t)ptB * 64 + ch);
      v1 = *(const float4*)(df + (size_t)ptB * 64 + ch + 4);
    } else {
      int c2 = ch - 64;
      float4 y0 = *(const float4*)(ysim + (size_t)ptB * 64 + c2);
      float4 y1 = *(const float4*)(ysim + (size_t)ptB * 64 + c2 + 4);
      v0.x = fmaxf(scs[c2] * y0.x + shs[c2], 0.f);
      v0.y = fmaxf(scs[c2 + 1] * y0.y + shs[c2 + 1], 0.f);
      v0.z = fmaxf(scs[c2 + 2] * y0.z + shs[c2 + 2], 0.f);
      v0.w = fmaxf(scs[c2 + 3] * y0.w + shs[c2 + 3], 0.f);
      v1.x = fmaxf(scs[c2 + 4] * y1.x + shs[c2 + 4], 0.f);
      v1.y = fmaxf(scs[c2 + 5] * y1.y + shs[c2 + 5], 0.f);
      v1.z = fmaxf(scs[c2 + 6] * y1.z + shs[c2 + 6], 0.f);
      v1.w = fmaxf(scs[c2 + 7] * y1.w + shs[c2 + 7], 0.f);
    }
    unsigned u4[4] = {pack_bf16x2(v0.x, v0.y), pack_bf16x2(v0.z, v0.w),
                      pack_bf16x2(v1.x, v1.y), pack_bf16x2(v1.z, v1.w)};
    pb[kk] = *(const v8bf*)u4;
  }
#pragma unroll
  for (int jb = 0; jb < 8; jb++) {
    int jrow = jb * 16 + lr;
    v4f a4 = {0, 0, 0, 0};
#pragma unroll
    for (int kk = 0; kk < 4; kk++) {
      v8bf wfrag = *(const v8bf*)(Wcomb + (size_t)jrow * 64 + kk * 16 + lg * 4);
      a4 = __builtin_amdgcn_mfma_f32_16x16x32_bf16(wfrag, pb[kk], a4, 0, 0, 0);
    }
    uint2 pk = make_uint2(pack_bf16x2(a4[0], a4[1]), pack_bf16x2(a4[2], a4[3]));
    *(uint2*)(yfb + (size_t)ptB * 64 + jb * 8 + lg * 2) = pk;
    float s0 = a4[0], s1 = a4[1], s2 = a4[2], s3 = a4[3];
    float q0 = s0 * s0, q1 = s1 * s1, q2 = s2 * s2, q3 = s3 * s3;
#define R4(x)              \
  x += __shfl_xor(x, 1);   \
  x += __shfl_xor(x, 2);   \
  x += __shfl_xor(x, 4);   \
  x += __shfl_xor(x, 8);
    R4(s0) R4(s1) R4(s2) R4(s3) R4(q0) R4(q1) R4(q2) R4(q3)
#undef R4
    if (lr == 0) {
      int j0 = jb * 16 + lg * 4;
      redS[wave][j0] = s0;
      redS[wave][j0 + 1] = s1;
      redS[wave][j0 + 2] = s2;
      redS[wave][j0 + 3] = s3;
      redQ[wave][j0] = q0;
      redQ[wave][j0 + 1] = q1;
      redQ[wave][j0 + 2] = q2;
      redQ[wave][j0 + 3] = q3;
    }
  }
  __syncthreads();
  if (t < 128) {
    atomicAdd(accF + t, redS[0][t] + redS[1][t] + redS[2][t] + redS[3][t]);
    atomicAdd(accF + 128 + t, redQ[0][t] + redQ[1][t] + redQ[2][t] + redQ[3][t]);
  }
}

// ---------------- out = relu(bn(YFb)) @ fw2^T + fb2 (MFMA, bf16 tiles) ------------
__global__ __launch_bounds__(256) void finout_gemm(
    const unsigned* __restrict__ YF0b, const unsigned* __restrict__ YF1b,
    const float* __restrict__ acc, const float* __restrict__ fg,
    const float* __restrict__ fbe, const float* __restrict__ fw2,
    const float* __restrict__ fb2, float* __restrict__ out) {
  int dir = blockIdx.y;
  const unsigned* yfb = dir ? YF1b : YF0b;
  const float* aF = acc + 512 + dir * 256;
  float* outp = out + (size_t)dir * NPTS * 64;
  __shared__ __align__(16) unsigned Au[64 * 68];
  __shared__ __align__(16) unsigned Bu[64 * 68];
  __shared__ float scl[128], shf[128], bb[64];
  int t = threadIdx.x;
  if (t < 128) {
    float mu = aF[t] / (float)NPTS;
    float var = aF[128 + t] / (float)NPTS - mu * mu;
    float scale = fg[t] * rsqrtf(var + EPSf);
    scl[t] = scale;
    shf[t] = fbe[t] - mu * scale;
  }
  if (t < 64) bb[t] = fb2[t];
  int ptb = blockIdx.x * 64;
#pragma unroll
  for (int i = 0; i < 16; i++) {
    int ix = t + i * 256;
    int row = ix >> 6, uc = ix & 63;
    int sw = uc ^ ((row & 7) << 2);
    float2 w = *(const float2*)(fw2 + (size_t)row * 128 + uc * 2);
    Bu[row * 68 + sw] = pack_bf16x2(w.x, w.y);
  }
  __syncthreads();  // scl/shf ready
#pragma unroll
  for (int i = 0; i < 16; i++) {
    int ix = t + i * 256;
    int row = ix >> 6, uc = ix & 63;
    int sw = uc ^ ((row & 7) << 2);
    unsigned uv = yfb[(size_t)(ptb + row) * 64 + uc];
    float h0 = fmaxf(scl[uc * 2] * bf16_lo(uv) + shf[uc * 2], 0.f);
    float h1 = fmaxf(scl[uc * 2 + 1] * bf16_hi(uv) + shf[uc * 2 + 1], 0.f);
    Au[row * 68 + sw] = pack_bf16x2(h0, h1);
  }
  __syncthreads();
  int wave = t >> 6, lane = t & 63, lr = lane & 15, lg = lane >> 4;
  v8bf a[4];
  {
    int arow = wave * 16 + lr;
    int base = arow * 68, sx = (arow & 7) << 2;
#pragma unroll
    for (int kk = 0; kk < 4; kk++)
      a[kk] = *(const v8bf*)&Au[base + ((kk * 16 + lg * 4) ^ sx)];
  }
  v4f acc4[4] = {{0, 0, 0, 0}, {0, 0, 0, 0}, {0, 0, 0, 0}, {0, 0, 0, 0}};
#pragma unroll
  for (int c = 0; c < 4; c++) {
    int brow = c * 16 + lr;
    int base = brow * 68, sx = (brow & 7) << 2;
#pragma unroll
    for (int kk = 0; kk < 4; kk++) {
      v8bf b = *(const v8bf*)&Bu[base + ((kk * 16 + lg * 4) ^ sx)];
      acc4[c] = __builtin_amdgcn_mfma_f32_16x16x32_bf16(a[kk], b, acc4[c], 0, 0, 0);
    }
  }
#pragma unroll
  for (int c = 0; c < 4; c++) {
    float bbv = bb[c * 16 + lr];
#pragma unroll
    for (int i = 0; i < 4; i++)
      outp[(size_t)(ptb + wave * 16 + lg * 4 + i) * 64 + c * 16 + lr] =
          acc4[c][i] + bbv;
  }
}

extern "C" void kernel_launch(void* const* d_in, const int* in_sizes, int n_in,
                              void* d_out, int out_size, void* d_ws, size_t ws_size,
                              hipStream_t stream) {
  const float* f0 = (const float*)d_in[0];
  const float* f1 = (const float*)d_in[1];
  const int* i01 = (const int*)d_in[2];
  const int* i10 = (const int*)d_in[3];
  const float* dw1 = (const float*)d_in[4];
  const float* dg = (const float*)d_in[6];
  const float* dbe = (const float*)d_in[7];
  const float* dw2 = (const float*)d_in[8];
  const float* db2 = (const float*)d_in[9];
  const float* sw1 = (const float*)d_in[10];
  const float* sg = (const float*)d_in[12];
  const float* sbe = (const float*)d_in[13];
  const float* sw2 = (const float*)d_in[14];
  const float* sb2 = (const float*)d_in[15];
  const float* fw1 = (const float*)d_in[16];
  const float* fg = (const float*)d_in[18];
  const float* fbe = (const float*)d_in[19];
  const float* fw2 = (const float*)d_in[20];
  const float* fb2 = (const float*)d_in[21];
  (void)sb2;  // cancels exactly under fin-BN after the W' fold

  char* wsb = (char*)d_ws;
  float* out = (float*)d_out;

  char* FT0 = wsb;                 // 12 MB + pad
  char* FT1 = wsb + FTSZ;          // 12 MB + pad
  float* acc = (float*)(wsb + 2 * FTSZ);              // 1024 floats
  float* Wp = (float*)(wsb + 2 * FTSZ + 16384);       // 128x64 fp32 = 32KB
  unsigned* Wcomb = (unsigned*)(wsb + 2 * FTSZ + 49152);  // 128x64 u32 = 32KB
  unsigned* Wc2 = (unsigned*)(wsb + 2 * FTSZ + 81920);    // 64x32 u32 = 8KB
  float* YS0 = (float*)(wsb + 2 * FTSZ + 131072);
  float* YS1 = YS0 + GSZ;
  float* DF0 = YS1 + GSZ;
  float* DF1 = DF0 + GSZ;
  unsigned* YF0b = (unsigned*)(DF1 + GSZ);        // 8 MB (bf16 YF)
  unsigned* YF1b = YF0b + (size_t)NPTS * 64;      // 8 MB

  hipMemsetAsync(acc, 0, 1024 * sizeof(float), stream);
  wprep<<<32, 256, 0, stream>>>(fw1, sw2, Wp);
  wpack<<<32, 256, 0, stream>>>(fw1, Wp, Wcomb);
  w2pack<<<8, 256, 0, stream>>>(dw2, Wc2);
  gemmG<<<dim3(512, 1, 2), 256, 0, stream>>>(f0, f1, dw1, sw1, FT0, FT1);

  stats_sim<<<2048, 256, 0, stream>>>(FT0, FT1, i01, i10, YS0, YS1, acc);

  diff_out_k<<<4096, 256, 0, stream>>>(FT0, FT1, i01, i10, Wc2, db2, acc, dg, dbe,
                                       DF0, DF1);

  yfin_gemm<<<dim3(512, 2), 256, 0, stream>>>(DF0, DF1, YS0, YS1, Wcomb, sg, sbe,
                                              YF0b, YF1b, acc);

  finout_gemm<<<dim3(512, 2), 256, 0, stream>>>(YF0b, YF1b, acc, fg, fbe, fw2, fb2, out);
}

// Round 24
// 160.239 us; speedup vs baseline: 1.2117x; 1.2117x over previous
//
#include <hip/hip_runtime.h>
#include <hip/hip_fp16.h>

// PointSetDifferenceModule: B=4, N=8192, C=64, K=16
// Round 24: revert diff_out_k to round-22 LDS version (44.5us known-good;
// r23's LDS-free variant serialized gather->MFMA and dropped occupancy ->81us).
// Everything else = r22/r23 lineage (yfin LDS-free, bf16 YF, W' fold).
// FT row (384B): [ f fp16 x64 | G_d bf16 x64 | G_s bf16 x64 ]

#define Bn 4
#define Nn 8192
#define NPTS (Bn * Nn)        // 32768
#define NSAMP (NPTS * 16)     // 524288
#define EPSf 1e-5f
#define FT_STRIDE 384
#define FTSZ ((size_t)NPTS * FT_STRIDE + 1024)
#define GSZ (NPTS * 64)

typedef __attribute__((ext_vector_type(8))) short v8bf;
typedef __attribute__((ext_vector_type(4))) float v4f;
typedef __attribute__((ext_vector_type(2))) _Float16 v2h;

union U2H {
  unsigned u;
  v2h h;
};

__device__ inline unsigned pack_bf16x2(float a, float b) {
  unsigned ua = __float_as_uint(a), ub = __float_as_uint(b);
  ua = (ua + 0x7FFFu + ((ua >> 16) & 1u)) >> 16;
  ub = (ub + 0x7FFFu + ((ub >> 16) & 1u)) >> 16;
  return (ub << 16) | ua;
}
__device__ inline float bf16_lo(unsigned u) { return __uint_as_float(u << 16); }
__device__ inline float bf16_hi(unsigned u) { return __uint_as_float(u & 0xFFFF0000u); }

__device__ inline float dot2acc(unsigned a, unsigned b, float c) {
  U2H ua, ub;
  ua.u = a;
  ub.u = b;
#if __has_builtin(__builtin_amdgcn_fdot2)
  return __builtin_amdgcn_fdot2(ua.h, ub.h, c, false);
#else
  return c + (float)ua.h.x * (float)ub.h.x + (float)ua.h.y * (float)ub.h.y;
#endif
}

// ---------------- W' = fw1[:,64:128] @ sw2  (128x64, fp32) ----------------
__global__ void wprep(const float* __restrict__ fw1, const float* __restrict__ sw2,
                      float* __restrict__ Wp) {
  int gid = blockIdx.x * 256 + threadIdx.x;  // 8192
  int j = gid >> 6, k = gid & 63;
  float s = 0.f;
#pragma unroll 8
  for (int c = 0; c < 64; c++) s += fw1[j * 128 + 64 + c] * sw2[c * 64 + k];
  Wp[gid] = s;
}

// ---------------- Wcomb[j][u] = pack_bf16( [fw1L | Wp][j][2u..2u+1] ) ------------
__global__ void wpack(const float* __restrict__ fw1, const float* __restrict__ Wp,
                      unsigned* __restrict__ Wcomb) {
  int gid = blockIdx.x * 256 + threadIdx.x;  // 8192
  int j = gid >> 6, u = gid & 63;
  int c = u * 2;
  float a, b;
  if (c < 64) {
    a = fw1[j * 128 + c];
    b = fw1[j * 128 + c + 1];
  } else {
    a = Wp[j * 64 + (c - 64)];
    b = Wp[j * 64 + (c - 64) + 1];
  }
  Wcomb[gid] = pack_bf16x2(a, b);
}

// ---------------- build fused tables: f fp16 + G_d, G_s bf16 ----------------
__global__ __launch_bounds__(256) void gemmG(const float* __restrict__ f0,
                                             const float* __restrict__ f1,
                                             const float* __restrict__ wd,
                                             const float* __restrict__ wsim,
                                             char* __restrict__ FT0,
                                             char* __restrict__ FT1) {
  int z = blockIdx.z;
  const float* F = z ? f1 : f0;
  char* FT = z ? FT1 : FT0;
  __shared__ float Fl[64][65];
  __shared__ float Wd[64][65];
  __shared__ float Ws[64][65];
  int t = threadIdx.x;
#pragma unroll
  for (int i = 0; i < 16; i++) {
    int ix = t + i * 256;
    Wd[ix >> 6][ix & 63] = wd[ix];
    Ws[ix >> 6][ix & 63] = wsim[ix];
  }
  int ptb = blockIdx.x * 64;
#pragma unroll
  for (int i = 0; i < 8; i++) {
    int pr = t + i * 256;  // pair index 0..2047
    int row = pr >> 5, c2 = pr & 31;
    float2 v = *(const float2*)(F + (size_t)(ptb + row) * 64 + c2 * 2);
    Fl[row][c2 * 2] = v.x;
    Fl[row][c2 * 2 + 1] = v.y;
    __half2 h2 = __floats2half2_rn(v.x, v.y);
    *(unsigned*)(FT + (size_t)(ptb + row) * FT_STRIDE + c2 * 4) =
        *reinterpret_cast<unsigned*>(&h2);
  }
  __syncthreads();
  int ty = t >> 4, tx = t & 15, r0 = ty * 4, c0 = tx * 4;
  float ad[4][4] = {}, as_[4][4] = {};
#pragma unroll 4
  for (int j = 0; j < 64; ++j) {
    float a[4], w1[4], w2[4];
#pragma unroll
    for (int i = 0; i < 4; i++) a[i] = Fl[r0 + i][j];
#pragma unroll
    for (int m = 0; m < 4; m++) {
      w1[m] = Wd[c0 + m][j];
      w2[m] = Ws[c0 + m][j];
    }
#pragma unroll
    for (int i = 0; i < 4; i++)
#pragma unroll
      for (int m = 0; m < 4; m++) {
        ad[i][m] += a[i] * w1[m];
        as_[i][m] += a[i] * w2[m];
      }
  }
#pragma unroll
  for (int i = 0; i < 4; i++) {
    char* row = FT + (size_t)(ptb + r0 + i) * FT_STRIDE;
    uint2 gd2 = make_uint2(pack_bf16x2(ad[i][0], ad[i][1]),
                           pack_bf16x2(ad[i][2], ad[i][3]));
    *(uint2*)(row + 128 + c0 * 2) = gd2;
    uint2 gs2 = make_uint2(pack_bf16x2(as_[i][0], as_[i][1]),
                           pack_bf16x2(as_[i][2], as_[i][3]));
    *(uint2*)(row + 256 + c0 * 2) = gs2;
  }
}

// ---------------- diff stats + sim softmax + y_sim (8 points per wave) ----------
__global__ __launch_bounds__(256) void stats_sim(
    const char* __restrict__ FT0, const char* __restrict__ FT1,
    const int* __restrict__ i01, const int* __restrict__ i10,
    float* __restrict__ YS0, float* __restrict__ YS1, float* __restrict__ acc) {
  int u = blockIdx.x & 7;
  int dir = u & 1, batch = u >> 1;
  const char* FS = dir ? FT1 : FT0;
  const char* FO = dir ? FT0 : FT1;
  const int* idx = dir ? i10 : i01;
  float* ys = dir ? YS1 : YS0;
  float* accDiff = acc + dir * 128;
  float* accSim = acc + 256 + dir * 128;
  int lane = threadIdx.x & 63, wave = threadIdx.x >> 6;
  int s = lane & 7, g = lane >> 3;
  int ptbase = batch * Nn + (blockIdx.x >> 3) * 32 + wave * 8;
  int bbase = batch * Nn;
  int myidx0 = idx[ptbase * 16 + lane];
  int myidx1 = idx[ptbase * 16 + 64 + lane];
  const char* srow = FS + (size_t)(ptbase + g) * FT_STRIDE;
  uint4 fs4 = *(const uint4*)(srow + s * 16);
  uint4 gds4 = *(const uint4*)(srow + 128 + s * 16);
  float gds[8] = {bf16_lo(gds4.x), bf16_hi(gds4.x), bf16_lo(gds4.y), bf16_hi(gds4.y),
                  bf16_lo(gds4.z), bf16_hi(gds4.z), bf16_lo(gds4.w), bf16_hi(gds4.w)};
  const char* ob = FO + (size_t)bbase * FT_STRIDE;
  int gq = (g & 3) * 16;
  bool hi = g >= 4;
  float S1[8] = {0, 0, 0, 0, 0, 0, 0, 0};
  float S2[8] = {0, 0, 0, 0, 0, 0, 0, 0};
  float ya[8] = {0, 0, 0, 0, 0, 0, 0, 0};
  float den = 0.f;
#pragma unroll 1
  for (int kc = 0; kc < 16; kc += 4) {
    uint4 fo[4], gdo[4], gso[4];
#pragma unroll
    for (int k = 0; k < 4; k++) {
      int jA = __shfl(myidx0, gq + kc + k);
      int jB = __shfl(myidx1, gq + kc + k);
      int j = hi ? jB : jA;
      const char* orow = ob + (size_t)j * FT_STRIDE;
      fo[k] = *(const uint4*)(orow + s * 16);
      gdo[k] = *(const uint4*)(orow + 128 + s * 16);
      gso[k] = *(const uint4*)(orow + 256 + s * 16);
    }
    float sims[4];
#pragma unroll
    for (int k = 0; k < 4; k++) {
      float p = dot2acc(fs4.x, fo[k].x, 0.f);
      p = dot2acc(fs4.y, fo[k].y, p);
      p = dot2acc(fs4.z, fo[k].z, p);
      p = dot2acc(fs4.w, fo[k].w, p);
      p += __shfl_xor(p, 4);
      p += __shfl_xor(p, 2);
      p += __shfl_xor(p, 1);
      sims[k] = p;
      float t0 = bf16_lo(gdo[k].x), t1 = bf16_hi(gdo[k].x);
      float t2 = bf16_lo(gdo[k].y), t3 = bf16_hi(gdo[k].y);
      float t4 = bf16_lo(gdo[k].z), t5 = bf16_hi(gdo[k].z);
      float t6 = bf16_lo(gdo[k].w), t7 = bf16_hi(gdo[k].w);
      S1[0] += t0; S2[0] += t0 * t0;
      S1[1] += t1; S2[1] += t1 * t1;
      S1[2] += t2; S2[2] += t2 * t2;
      S1[3] += t3; S2[3] += t3 * t3;
      S1[4] += t4; S2[4] += t4 * t4;
      S1[5] += t5; S2[5] += t5 * t5;
      S1[6] += t6; S2[6] += t6 * t6;
      S1[7] += t7; S2[7] += t7 * t7;
    }
#pragma unroll
    for (int k = 0; k < 4; k++) {
      float e = __expf(sims[k]);
      den += e;
      ya[0] += e * bf16_lo(gso[k].x);
      ya[1] += e * bf16_hi(gso[k].x);
      ya[2] += e * bf16_lo(gso[k].y);
      ya[3] += e * bf16_hi(gso[k].y);
      ya[4] += e * bf16_lo(gso[k].z);
      ya[5] += e * bf16_hi(gso[k].z);
      ya[6] += e * bf16_lo(gso[k].w);
      ya[7] += e * bf16_hi(gso[k].w);
    }
  }
  float inv = 1.f / den;
#pragma unroll
  for (int i = 0; i < 8; i++) ya[i] *= inv;
  float* yrow = ys + (size_t)(ptbase + g) * 64 + s * 8;
  *(float4*)(yrow) = make_float4(ya[0], ya[1], ya[2], ya[3]);
  *(float4*)(yrow + 4) = make_float4(ya[4], ya[5], ya[6], ya[7]);
  float sd[8], qd[8], qs[8];
#pragma unroll
  for (int i = 0; i < 8; i++) {
    sd[i] = 16.f * gds[i] - S1[i];
    qd[i] = 16.f * gds[i] * gds[i] - 2.f * gds[i] * S1[i] + S2[i];
    qs[i] = ya[i] * ya[i];
  }
#define GRED(x)           \
  x += __shfl_xor(x, 8);  \
  x += __shfl_xor(x, 16); \
  x += __shfl_xor(x, 32);
#pragma unroll
  for (int i = 0; i < 8; i++) {
    GRED(sd[i]) GRED(qd[i]) GRED(ya[i]) GRED(qs[i])
  }
#undef GRED
  __shared__ float red[4][4][64];
  if (lane < 8) {
#pragma unroll
    for (int i = 0; i < 8; i++) {
      red[wave][0][s * 8 + i] = sd[i];
      red[wave][1][s * 8 + i] = qd[i];
      red[wave][2][s * 8 + i] = ya[i];
      red[wave][3][s * 8 + i] = qs[i];
    }
  }
  __syncthreads();
  if (wave == 0) {
    float v = red[0][0][lane] + red[1][0][lane] + red[2][0][lane] + red[3][0][lane];
    atomicAdd(accDiff + lane, v);
    v = red[0][1][lane] + red[1][1][lane] + red[2][1][lane] + red[3][1][lane];
    atomicAdd(accDiff + 64 + lane, v);
    v = red[0][2][lane] + red[1][2][lane] + red[2][2][lane] + red[3][2][lane];
    atomicAdd(accSim + lane, v);
    v = red[0][3][lane] + red[1][3][lane] + red[2][3][lane] + red[3][3][lane];
    atomicAdd(accSim + 64 + lane, v);
  }
}

// ---------------- diff output: gather bf16 + BN/relu + MFMA GEMM + max over K --------
__global__ __launch_bounds__(256) void diff_out_k(
    const char* __restrict__ FT0, const char* __restrict__ FT1,
    const int* __restrict__ i01, const int* __restrict__ i10,
    const float* __restrict__ w2d, const float* __restrict__ b2d,
    const float* __restrict__ acc, const float* __restrict__ dg,
    const float* __restrict__ dbe, float* __restrict__ DF0, float* __restrict__ DF1) {
  int u = blockIdx.x & 7;
  int dir = u & 1, batch = u >> 1;
  const char* FS = dir ? FT1 : FT0;
  const char* FO = dir ? FT0 : FT1;
  const int* idx = dir ? i10 : i01;
  const float* aD = acc + dir * 128;
  float* dout = dir ? DF1 : DF0;
  __shared__ __align__(16) unsigned WlU[64 * 36];
  __shared__ __align__(16) unsigned HtU[64 * 36];
  __shared__ unsigned Gs[4][32];
  __shared__ int idxt[64];
  __shared__ float sc[64], sh[64], bb[64];
  int t = threadIdx.x;
  int r = t >> 2, q = t & 3;
  {
    const float4* w4 = (const float4*)(w2d + r * 64 + q * 16);
#pragma unroll
    for (int uu = 0; uu < 4; uu++) {
      float4 v = w4[uu];
      WlU[r * 36 + q * 8 + uu * 2] = pack_bf16x2(v.x, v.y);
      WlU[r * 36 + q * 8 + uu * 2 + 1] = pack_bf16x2(v.z, v.w);
    }
  }
  if (t < 64) {
    float mu = aD[t] / (float)NSAMP;
    float var = aD[64 + t] / (float)NSAMP - mu * mu;
    float scale = dg[t] * rsqrtf(var + EPSf);
    sc[t] = scale;
    sh[t] = dbe[t] - mu * scale;
    bb[t] = b2d[t];
  }
  int wave = t >> 6, lane = t & 63;
  int lr = lane & 15, lg = lane >> 4;
  int p = r >> 4;
  int wblk = blockIdx.x >> 3;  // 0..511
  int bbase = batch * Nn;
#pragma unroll 1
  for (int tt = 0; tt < 4; tt++) {
    int tile = wblk * 4 + tt;
    int ptb = batch * Nn + tile * 4;
    __syncthreads();
    if (t < 64) idxt[t] = idx[ptb * 16 + t];
    if (t < 128)
      Gs[t >> 5][t & 31] =
          *(const unsigned*)(FS + (size_t)(ptb + (t >> 5)) * FT_STRIDE + 128 + (t & 31) * 4);
    __syncthreads();
    const char* orow = FO + (size_t)(bbase + idxt[r]) * FT_STRIDE + 128;
    uint4 g0 = *(const uint4*)(orow + q * 32);
    uint4 g1 = *(const uint4*)(orow + q * 32 + 16);
#pragma unroll
    for (int uu = 0; uu < 8; uu++) {
      unsigned gdo2 = (uu < 4) ? ((const unsigned*)&g0)[uu] : ((const unsigned*)&g1)[uu - 4];
      unsigned gds2 = Gs[p][q * 8 + uu];
      int c = q * 16 + uu * 2;
      float h0 = fmaxf(sc[c] * (bf16_lo(gds2) - bf16_lo(gdo2)) + sh[c], 0.f);
      float h1 = fmaxf(sc[c + 1] * (bf16_hi(gds2) - bf16_hi(gdo2)) + sh[c + 1], 0.f);
      HtU[r * 36 + q * 8 + uu] = pack_bf16x2(h0, h1);
    }
    __syncthreads();
    v4f acc4[4] = {{0, 0, 0, 0}, {0, 0, 0, 0}, {0, 0, 0, 0}, {0, 0, 0, 0}};
    v8bf a0 = *(const v8bf*)&HtU[(wave * 16 + lr) * 36 + lg * 4];
    v8bf a1 = *(const v8bf*)&HtU[(wave * 16 + lr) * 36 + 16 + lg * 4];
#pragma unroll
    for (int c = 0; c < 4; c++) {
      v8bf b0 = *(const v8bf*)&WlU[(c * 16 + lr) * 36 + lg * 4];
      v8bf b1 = *(const v8bf*)&WlU[(c * 16 + lr) * 36 + 16 + lg * 4];
      acc4[c] = __builtin_amdgcn_mfma_f32_16x16x32_bf16(a0, b0, acc4[c], 0, 0, 0);
      acc4[c] = __builtin_amdgcn_mfma_f32_16x16x32_bf16(a1, b1, acc4[c], 0, 0, 0);
    }
#pragma unroll
    for (int c = 0; c < 4; c++) {
      float mm = fmaxf(fmaxf(acc4[c][0], acc4[c][1]), fmaxf(acc4[c][2], acc4[c][3]));
      mm = fmaxf(mm, __shfl_xor(mm, 16));
      mm = fmaxf(mm, __shfl_xor(mm, 32));
      if (lane < 16) dout[(size_t)(ptb + wave) * 64 + c * 16 + lane] = mm + bb[c * 16 + lane];
    }
  }
}

// ---- YF(bf16) = [DF | relu_bn(YS)] @ [fw1L | W']^T + fin BN stats (LDS-free) ----
__global__ __launch_bounds__(256) void yfin_gemm(
    const float* __restrict__ DF0, const float* __restrict__ DF1,
    const float* __restrict__ YS0, const float* __restrict__ YS1,
    const unsigned* __restrict__ Wcomb, const float* __restrict__ sg,
    const float* __restrict__ sbe, unsigned* __restrict__ YF0b,
    unsigned* __restrict__ YF1b, float* __restrict__ acc) {
  int dir = blockIdx.y;
  const float* df = dir ? DF1 : DF0;
  const float* ysim = dir ? YS1 : YS0;
  unsigned* yfb = dir ? YF1b : YF0b;
  const float* aS = acc + 256 + dir * 128;
  float* accF = acc + 512 + dir * 256;
  __shared__ float redS[4][128], redQ[4][128];
  __shared__ float scs[64], shs[64];
  int t = threadIdx.x;
  int ptb = blockIdx.x * 64;
  if (t < 64) {
    float mu = aS[t] / (float)NPTS;
    float var = aS[64 + t] / (float)NPTS - mu * mu;
    float scale = sg[t] * rsqrtf(var + EPSf);
    scs[t] = scale;
    shs[t] = sbe[t] - mu * scale;
  }
  __syncthreads();
  int wave = t >> 6, lane = t & 63, lr = lane & 15, lg = lane >> 4;
  int ptB = ptb + wave * 16 + lr;
  v8bf pb[4];
#pragma unroll
  for (int kk = 0; kk < 4; kk++) {
    int ch = kk * 32 + lg * 8;
    float4 v0, v1;
    if (ch < 64) {
      v0 = *(const float4*)(df + (size_t)ptB * 64 + ch);
      v1 = *(const float4*)(df + (size_t)ptB * 64 + ch + 4);
    } else {
      int c2 = ch - 64;
      float4 y0 = *(const float4*)(ysim + (size_t)ptB * 64 + c2);
      float4 y1 = *(const float4*)(ysim + (size_t)ptB * 64 + c2 + 4);
      v0.x = fmaxf(scs[c2] * y0.x + shs[c2], 0.f);
      v0.y = fmaxf(scs[c2 + 1] * y0.y + shs[c2 + 1], 0.f);
      v0.z = fmaxf(scs[c2 + 2] * y0.z + shs[c2 + 2], 0.f);
      v0.w = fmaxf(scs[c2 + 3] * y0.w + shs[c2 + 3], 0.f);
      v1.x = fmaxf(scs[c2 + 4] * y1.x + shs[c2 + 4], 0.f);
      v1.y = fmaxf(scs[c2 + 5] * y1.y + shs[c2 + 5], 0.f);
      v1.z = fmaxf(scs[c2 + 6] * y1.z + shs[c2 + 6], 0.f);
      v1.w = fmaxf(scs[c2 + 7] * y1.w + shs[c2 + 7], 0.f);
    }
    unsigned u4[4] = {pack_bf16x2(v0.x, v0.y), pack_bf16x2(v0.z, v0.w),
                      pack_bf16x2(v1.x, v1.y), pack_bf16x2(v1.z, v1.w)};
    pb[kk] = *(const v8bf*)u4;
  }
#pragma unroll
  for (int jb = 0; jb < 8; jb++) {
    int jrow = jb * 16 + lr;
    v4f a4 = {0, 0, 0, 0};
#pragma unroll
    for (int kk = 0; kk < 4; kk++) {
      v8bf wfrag = *(const v8bf*)(Wcomb + (size_t)jrow * 64 + kk * 16 + lg * 4);
      a4 = __builtin_amdgcn_mfma_f32_16x16x32_bf16(wfrag, pb[kk], a4, 0, 0, 0);
    }
    uint2 pk = make_uint2(pack_bf16x2(a4[0], a4[1]), pack_bf16x2(a4[2], a4[3]));
    *(uint2*)(yfb + (size_t)ptB * 64 + jb * 8 + lg * 2) = pk;
    float s0 = a4[0], s1 = a4[1], s2 = a4[2], s3 = a4[3];
    float q0 = s0 * s0, q1 = s1 * s1, q2 = s2 * s2, q3 = s3 * s3;
#define R4(x)              \
  x += __shfl_xor(x, 1);   \
  x += __shfl_xor(x, 2);   \
  x += __shfl_xor(x, 4);   \
  x += __shfl_xor(x, 8);
    R4(s0) R4(s1) R4(s2) R4(s3) R4(q0) R4(q1) R4(q2) R4(q3)
#undef R4
    if (lr == 0) {
      int j0 = jb * 16 + lg * 4;
      redS[wave][j0] = s0;
      redS[wave][j0 + 1] = s1;
      redS[wave][j0 + 2] = s2;
      redS[wave][j0 + 3] = s3;
      redQ[wave][j0] = q0;
      redQ[wave][j0 + 1] = q1;
      redQ[wave][j0 + 2] = q2;
      redQ[wave][j0 + 3] = q3;
    }
  }
  __syncthreads();
  if (t < 128) {
    atomicAdd(accF + t, redS[0][t] + redS[1][t] + redS[2][t] + redS[3][t]);
    atomicAdd(accF + 128 + t, redQ[0][t] + redQ[1][t] + redQ[2][t] + redQ[3][t]);
  }
}

// ---------------- out = relu(bn(YFb)) @ fw2^T + fb2 (MFMA, bf16 tiles) ------------
__global__ __launch_bounds__(256) void finout_gemm(
    const unsigned* __restrict__ YF0b, const unsigned* __restrict__ YF1b,
    const float* __restrict__ acc, const float* __restrict__ fg,
    const float* __restrict__ fbe, const float* __restrict__ fw2,
    const float* __restrict__ fb2, float* __restrict__ out) {
  int dir = blockIdx.y;
  const unsigned* yfb = dir ? YF1b : YF0b;
  const float* aF = acc + 512 + dir * 256;
  float* outp = out + (size_t)dir * NPTS * 64;
  __shared__ __align__(16) unsigned Au[64 * 68];
  __shared__ __align__(16) unsigned Bu[64 * 68];
  __shared__ float scl[128], shf[128], bb[64];
  int t = threadIdx.x;
  if (t < 128) {
    float mu = aF[t] / (float)NPTS;
    float var = aF[128 + t] / (float)NPTS - mu * mu;
    float scale = fg[t] * rsqrtf(var + EPSf);
    scl[t] = scale;
    shf[t] = fbe[t] - mu * scale;
  }
  if (t < 64) bb[t] = fb2[t];
  int ptb = blockIdx.x * 64;
#pragma unroll
  for (int i = 0; i < 16; i++) {
    int ix = t + i * 256;
    int row = ix >> 6, uc = ix & 63;
    int sw = uc ^ ((row & 7) << 2);
    float2 w = *(const float2*)(fw2 + (size_t)row * 128 + uc * 2);
    Bu[row * 68 + sw] = pack_bf16x2(w.x, w.y);
  }
  __syncthreads();  // scl/shf ready
#pragma unroll
  for (int i = 0; i < 16; i++) {
    int ix = t + i * 256;
    int row = ix >> 6, uc = ix & 63;
    int sw = uc ^ ((row & 7) << 2);
    unsigned uv = yfb[(size_t)(ptb + row) * 64 + uc];
    float h0 = fmaxf(scl[uc * 2] * bf16_lo(uv) + shf[uc * 2], 0.f);
    float h1 = fmaxf(scl[uc * 2 + 1] * bf16_hi(uv) + shf[uc * 2 + 1], 0.f);
    Au[row * 68 + sw] = pack_bf16x2(h0, h1);
  }
  __syncthreads();
  int wave = t >> 6, lane = t & 63, lr = lane & 15, lg = lane >> 4;
  v8bf a[4];
  {
    int arow = wave * 16 + lr;
    int base = arow * 68, sx = (arow & 7) << 2;
#pragma unroll
    for (int kk = 0; kk < 4; kk++)
      a[kk] = *(const v8bf*)&Au[base + ((kk * 16 + lg * 4) ^ sx)];
  }
  v4f acc4[4] = {{0, 0, 0, 0}, {0, 0, 0, 0}, {0, 0, 0, 0}, {0, 0, 0, 0}};
#pragma unroll
  for (int c = 0; c < 4; c++) {
    int brow = c * 16 + lr;
    int base = brow * 68, sx = (brow & 7) << 2;
#pragma unroll
    for (int kk = 0; kk < 4; kk++) {
      v8bf b = *(const v8bf*)&Bu[base + ((kk * 16 + lg * 4) ^ sx)];
      acc4[c] = __builtin_amdgcn_mfma_f32_16x16x32_bf16(a[kk], b, acc4[c], 0, 0, 0);
    }
  }
#pragma unroll
  for (int c = 0; c < 4; c++) {
    float bbv = bb[c * 16 + lr];
#pragma unroll
    for (int i = 0; i < 4; i++)
      outp[(size_t)(ptb + wave * 16 + lg * 4 + i) * 64 + c * 16 + lr] =
          acc4[c][i] + bbv;
  }
}

extern "C" void kernel_launch(void* const* d_in, const int* in_sizes, int n_in,
                              void* d_out, int out_size, void* d_ws, size_t ws_size,
                              hipStream_t stream) {
  const float* f0 = (const float*)d_in[0];
  const float* f1 = (const float*)d_in[1];
  const int* i01 = (const int*)d_in[2];
  const int* i10 = (const int*)d_in[3];
  const float* dw1 = (const float*)d_in[4];
  const float* dg = (const float*)d_in[6];
  const float* dbe = (const float*)d_in[7];
  const float* dw2 = (const float*)d_in[8];
  const float* db2 = (const float*)d_in[9];
  const float* sw1 = (const float*)d_in[10];
  const float* sg = (const float*)d_in[12];
  const float* sbe = (const float*)d_in[13];
  const float* sw2 = (const float*)d_in[14];
  const float* sb2 = (const float*)d_in[15];
  const float* fw1 = (const float*)d_in[16];
  const float* fg = (const float*)d_in[18];
  const float* fbe = (const float*)d_in[19];
  const float* fw2 = (const float*)d_in[20];
  const float* fb2 = (const float*)d_in[21];
  (void)sb2;  // cancels exactly under fin-BN after the W' fold

  char* wsb = (char*)d_ws;
  float* out = (float*)d_out;

  char* FT0 = wsb;                 // 12 MB + pad
  char* FT1 = wsb + FTSZ;          // 12 MB + pad
  float* acc = (float*)(wsb + 2 * FTSZ);              // 1024 floats
  float* Wp = (float*)(wsb + 2 * FTSZ + 16384);       // 128x64 fp32 = 32KB
  unsigned* Wcomb = (unsigned*)(wsb + 2 * FTSZ + 49152);  // 128x64 u32 = 32KB
  float* YS0 = (float*)(wsb + 2 * FTSZ + 131072);
  float* YS1 = YS0 + GSZ;
  float* DF0 = YS1 + GSZ;
  float* DF1 = DF0 + GSZ;
  unsigned* YF0b = (unsigned*)(DF1 + GSZ);        // 8 MB (bf16 YF)
  unsigned* YF1b = YF0b + (size_t)NPTS * 64;      // 8 MB

  hipMemsetAsync(acc, 0, 1024 * sizeof(float), stream);
  wprep<<<32, 256, 0, stream>>>(fw1, sw2, Wp);
  wpack<<<32, 256, 0, stream>>>(fw1, Wp, Wcomb);
  gemmG<<<dim3(512, 1, 2), 256, 0, stream>>>(f0, f1, dw1, sw1, FT0, FT1);

  stats_sim<<<2048, 256, 0, stream>>>(FT0, FT1, i01, i10, YS0, YS1, acc);

  diff_out_k<<<4096, 256, 0, stream>>>(FT0, FT1, i01, i10, dw2, db2, acc, dg, dbe,
                                       DF0, DF1);

  yfin_gemm<<<dim3(512, 2), 256, 0, stream>>>(DF0, DF1, YS0, YS1, Wcomb, sg, sbe,
                                              YF0b, YF1b, acc);

  finout_gemm<<<dim3(512, 2), 256, 0, stream>>>(YF0b, YF1b, acc, fg, fbe, fw2, fb2, out);
}

// Round 25
// 159.130 us; speedup vs baseline: 1.2201x; 1.0070x over previous
//
#include <hip/hip_runtime.h>
#include <hip/hip_fp16.h>

// PointSetDifferenceModule: B=4, N=8192, C=64, K=16
// Round 25: (1) diff_out_k HtU/WlU staging via ds_write_b128 pairs (was 8
// scalar u32 stores at 8-way bank conflict -> 2.6M conflict cycles);
// (2) acc zeroing folded into wprep (memset dispatch removed).
// Rest = round 24 (160.2us, absmax 0.03125).
// FT row (384B): [ f fp16 x64 | G_d bf16 x64 | G_s bf16 x64 ]

#define Bn 4
#define Nn 8192
#define NPTS (Bn * Nn)        // 32768
#define NSAMP (NPTS * 16)     // 524288
#define EPSf 1e-5f
#define FT_STRIDE 384
#define FTSZ ((size_t)NPTS * FT_STRIDE + 1024)
#define GSZ (NPTS * 64)

typedef __attribute__((ext_vector_type(8))) short v8bf;
typedef __attribute__((ext_vector_type(4))) float v4f;
typedef __attribute__((ext_vector_type(2))) _Float16 v2h;

union U2H {
  unsigned u;
  v2h h;
};

__device__ inline unsigned pack_bf16x2(float a, float b) {
  unsigned ua = __float_as_uint(a), ub = __float_as_uint(b);
  ua = (ua + 0x7FFFu + ((ua >> 16) & 1u)) >> 16;
  ub = (ub + 0x7FFFu + ((ub >> 16) & 1u)) >> 16;
  return (ub << 16) | ua;
}
__device__ inline float bf16_lo(unsigned u) { return __uint_as_float(u << 16); }
__device__ inline float bf16_hi(unsigned u) { return __uint_as_float(u & 0xFFFF0000u); }

__device__ inline float dot2acc(unsigned a, unsigned b, float c) {
  U2H ua, ub;
  ua.u = a;
  ub.u = b;
#if __has_builtin(__builtin_amdgcn_fdot2)
  return __builtin_amdgcn_fdot2(ua.h, ub.h, c, false);
#else
  return c + (float)ua.h.x * (float)ub.h.x + (float)ua.h.y * (float)ub.h.y;
#endif
}

// ------ W' = fw1[:,64:128] @ sw2 (128x64 fp32) + acc zeroing (folded memset) ------
__global__ void wprep(const float* __restrict__ fw1, const float* __restrict__ sw2,
                      float* __restrict__ Wp, float* __restrict__ acc) {
  int gid = blockIdx.x * 256 + threadIdx.x;  // 8192
  if (gid < 1024) acc[gid] = 0.f;
  int j = gid >> 6, k = gid & 63;
  float s = 0.f;
#pragma unroll 8
  for (int c = 0; c < 64; c++) s += fw1[j * 128 + 64 + c] * sw2[c * 64 + k];
  Wp[gid] = s;
}

// ---------------- Wcomb[j][u] = pack_bf16( [fw1L | Wp][j][2u..2u+1] ) ------------
__global__ void wpack(const float* __restrict__ fw1, const float* __restrict__ Wp,
                      unsigned* __restrict__ Wcomb) {
  int gid = blockIdx.x * 256 + threadIdx.x;  // 8192
  int j = gid >> 6, u = gid & 63;
  int c = u * 2;
  float a, b;
  if (c < 64) {
    a = fw1[j * 128 + c];
    b = fw1[j * 128 + c + 1];
  } else {
    a = Wp[j * 64 + (c - 64)];
    b = Wp[j * 64 + (c - 64) + 1];
  }
  Wcomb[gid] = pack_bf16x2(a, b);
}

// ---------------- build fused tables: f fp16 + G_d, G_s bf16 ----------------
__global__ __launch_bounds__(256) void gemmG(const float* __restrict__ f0,
                                             const float* __restrict__ f1,
                                             const float* __restrict__ wd,
                                             const float* __restrict__ wsim,
                                             char* __restrict__ FT0,
                                             char* __restrict__ FT1) {
  int z = blockIdx.z;
  const float* F = z ? f1 : f0;
  char* FT = z ? FT1 : FT0;
  __shared__ float Fl[64][65];
  __shared__ float Wd[64][65];
  __shared__ float Ws[64][65];
  int t = threadIdx.x;
#pragma unroll
  for (int i = 0; i < 16; i++) {
    int ix = t + i * 256;
    Wd[ix >> 6][ix & 63] = wd[ix];
    Ws[ix >> 6][ix & 63] = wsim[ix];
  }
  int ptb = blockIdx.x * 64;
#pragma unroll
  for (int i = 0; i < 8; i++) {
    int pr = t + i * 256;  // pair index 0..2047
    int row = pr >> 5, c2 = pr & 31;
    float2 v = *(const float2*)(F + (size_t)(ptb + row) * 64 + c2 * 2);
    Fl[row][c2 * 2] = v.x;
    Fl[row][c2 * 2 + 1] = v.y;
    __half2 h2 = __floats2half2_rn(v.x, v.y);
    *(unsigned*)(FT + (size_t)(ptb + row) * FT_STRIDE + c2 * 4) =
        *reinterpret_cast<unsigned*>(&h2);
  }
  __syncthreads();
  int ty = t >> 4, tx = t & 15, r0 = ty * 4, c0 = tx * 4;
  float ad[4][4] = {}, as_[4][4] = {};
#pragma unroll 4
  for (int j = 0; j < 64; ++j) {
    float a[4], w1[4], w2[4];
#pragma unroll
    for (int i = 0; i < 4; i++) a[i] = Fl[r0 + i][j];
#pragma unroll
    for (int m = 0; m < 4; m++) {
      w1[m] = Wd[c0 + m][j];
      w2[m] = Ws[c0 + m][j];
    }
#pragma unroll
    for (int i = 0; i < 4; i++)
#pragma unroll
      for (int m = 0; m < 4; m++) {
        ad[i][m] += a[i] * w1[m];
        as_[i][m] += a[i] * w2[m];
      }
  }
#pragma unroll
  for (int i = 0; i < 4; i++) {
    char* row = FT + (size_t)(ptb + r0 + i) * FT_STRIDE;
    uint2 gd2 = make_uint2(pack_bf16x2(ad[i][0], ad[i][1]),
                           pack_bf16x2(ad[i][2], ad[i][3]));
    *(uint2*)(row + 128 + c0 * 2) = gd2;
    uint2 gs2 = make_uint2(pack_bf16x2(as_[i][0], as_[i][1]),
                           pack_bf16x2(as_[i][2], as_[i][3]));
    *(uint2*)(row + 256 + c0 * 2) = gs2;
  }
}

// ---------------- diff stats + sim softmax + y_sim (8 points per wave) ----------
__global__ __launch_bounds__(256) void stats_sim(
    const char* __restrict__ FT0, const char* __restrict__ FT1,
    const int* __restrict__ i01, const int* __restrict__ i10,
    float* __restrict__ YS0, float* __restrict__ YS1, float* __restrict__ acc) {
  int u = blockIdx.x & 7;
  int dir = u & 1, batch = u >> 1;
  const char* FS = dir ? FT1 : FT0;
  const char* FO = dir ? FT0 : FT1;
  const int* idx = dir ? i10 : i01;
  float* ys = dir ? YS1 : YS0;
  float* accDiff = acc + dir * 128;
  float* accSim = acc + 256 + dir * 128;
  int lane = threadIdx.x & 63, wave = threadIdx.x >> 6;
  int s = lane & 7, g = lane >> 3;
  int ptbase = batch * Nn + (blockIdx.x >> 3) * 32 + wave * 8;
  int bbase = batch * Nn;
  int myidx0 = idx[ptbase * 16 + lane];
  int myidx1 = idx[ptbase * 16 + 64 + lane];
  const char* srow = FS + (size_t)(ptbase + g) * FT_STRIDE;
  uint4 fs4 = *(const uint4*)(srow + s * 16);
  uint4 gds4 = *(const uint4*)(srow + 128 + s * 16);
  float gds[8] = {bf16_lo(gds4.x), bf16_hi(gds4.x), bf16_lo(gds4.y), bf16_hi(gds4.y),
                  bf16_lo(gds4.z), bf16_hi(gds4.z), bf16_lo(gds4.w), bf16_hi(gds4.w)};
  const char* ob = FO + (size_t)bbase * FT_STRIDE;
  int gq = (g & 3) * 16;
  bool hi = g >= 4;
  float S1[8] = {0, 0, 0, 0, 0, 0, 0, 0};
  float S2[8] = {0, 0, 0, 0, 0, 0, 0, 0};
  float ya[8] = {0, 0, 0, 0, 0, 0, 0, 0};
  float den = 0.f;
#pragma unroll 1
  for (int kc = 0; kc < 16; kc += 4) {
    uint4 fo[4], gdo[4], gso[4];
#pragma unroll
    for (int k = 0; k < 4; k++) {
      int jA = __shfl(myidx0, gq + kc + k);
      int jB = __shfl(myidx1, gq + kc + k);
      int j = hi ? jB : jA;
      const char* orow = ob + (size_t)j * FT_STRIDE;
      fo[k] = *(const uint4*)(orow + s * 16);
      gdo[k] = *(const uint4*)(orow + 128 + s * 16);
      gso[k] = *(const uint4*)(orow + 256 + s * 16);
    }
    float sims[4];
#pragma unroll
    for (int k = 0; k < 4; k++) {
      float p = dot2acc(fs4.x, fo[k].x, 0.f);
      p = dot2acc(fs4.y, fo[k].y, p);
      p = dot2acc(fs4.z, fo[k].z, p);
      p = dot2acc(fs4.w, fo[k].w, p);
      p += __shfl_xor(p, 4);
      p += __shfl_xor(p, 2);
      p += __shfl_xor(p, 1);
      sims[k] = p;
      float t0 = bf16_lo(gdo[k].x), t1 = bf16_hi(gdo[k].x);
      float t2 = bf16_lo(gdo[k].y), t3 = bf16_hi(gdo[k].y);
      float t4 = bf16_lo(gdo[k].z), t5 = bf16_hi(gdo[k].z);
      float t6 = bf16_lo(gdo[k].w), t7 = bf16_hi(gdo[k].w);
      S1[0] += t0; S2[0] += t0 * t0;
      S1[1] += t1; S2[1] += t1 * t1;
      S1[2] += t2; S2[2] += t2 * t2;
      S1[3] += t3; S2[3] += t3 * t3;
      S1[4] += t4; S2[4] += t4 * t4;
      S1[5] += t5; S2[5] += t5 * t5;
      S1[6] += t6; S2[6] += t6 * t6;
      S1[7] += t7; S2[7] += t7 * t7;
    }
#pragma unroll
    for (int k = 0; k < 4; k++) {
      float e = __expf(sims[k]);
      den += e;
      ya[0] += e * bf16_lo(gso[k].x);
      ya[1] += e * bf16_hi(gso[k].x);
      ya[2] += e * bf16_lo(gso[k].y);
      ya[3] += e * bf16_hi(gso[k].y);
      ya[4] += e * bf16_lo(gso[k].z);
      ya[5] += e * bf16_hi(gso[k].z);
      ya[6] += e * bf16_lo(gso[k].w);
      ya[7] += e * bf16_hi(gso[k].w);
    }
  }
  float inv = 1.f / den;
#pragma unroll
  for (int i = 0; i < 8; i++) ya[i] *= inv;
  float* yrow = ys + (size_t)(ptbase + g) * 64 + s * 8;
  *(float4*)(yrow) = make_float4(ya[0], ya[1], ya[2], ya[3]);
  *(float4*)(yrow + 4) = make_float4(ya[4], ya[5], ya[6], ya[7]);
  float sd[8], qd[8], qs[8];
#pragma unroll
  for (int i = 0; i < 8; i++) {
    sd[i] = 16.f * gds[i] - S1[i];
    qd[i] = 16.f * gds[i] * gds[i] - 2.f * gds[i] * S1[i] + S2[i];
    qs[i] = ya[i] * ya[i];
  }
#define GRED(x)           \
  x += __shfl_xor(x, 8);  \
  x += __shfl_xor(x, 16); \
  x += __shfl_xor(x, 32);
#pragma unroll
  for (int i = 0; i < 8; i++) {
    GRED(sd[i]) GRED(qd[i]) GRED(ya[i]) GRED(qs[i])
  }
#undef GRED
  __shared__ float red[4][4][64];
  if (lane < 8) {
#pragma unroll
    for (int i = 0; i < 8; i++) {
      red[wave][0][s * 8 + i] = sd[i];
      red[wave][1][s * 8 + i] = qd[i];
      red[wave][2][s * 8 + i] = ya[i];
      red[wave][3][s * 8 + i] = qs[i];
    }
  }
  __syncthreads();
  if (wave == 0) {
    float v = red[0][0][lane] + red[1][0][lane] + red[2][0][lane] + red[3][0][lane];
    atomicAdd(accDiff + lane, v);
    v = red[0][1][lane] + red[1][1][lane] + red[2][1][lane] + red[3][1][lane];
    atomicAdd(accDiff + 64 + lane, v);
    v = red[0][2][lane] + red[1][2][lane] + red[2][2][lane] + red[3][2][lane];
    atomicAdd(accSim + lane, v);
    v = red[0][3][lane] + red[1][3][lane] + red[2][3][lane] + red[3][3][lane];
    atomicAdd(accSim + 64 + lane, v);
  }
}

// ---------------- diff output: gather bf16 + BN/relu + MFMA GEMM + max over K --------
__global__ __launch_bounds__(256) void diff_out_k(
    const char* __restrict__ FT0, const char* __restrict__ FT1,
    const int* __restrict__ i01, const int* __restrict__ i10,
    const float* __restrict__ w2d, const float* __restrict__ b2d,
    const float* __restrict__ acc, const float* __restrict__ dg,
    const float* __restrict__ dbe, float* __restrict__ DF0, float* __restrict__ DF1) {
  int u = blockIdx.x & 7;
  int dir = u & 1, batch = u >> 1;
  const char* FS = dir ? FT1 : FT0;
  const char* FO = dir ? FT0 : FT1;
  const int* idx = dir ? i10 : i01;
  const float* aD = acc + dir * 128;
  float* dout = dir ? DF1 : DF0;
  __shared__ __align__(16) unsigned WlU[64 * 36];
  __shared__ __align__(16) unsigned HtU[64 * 36];
  __shared__ unsigned Gs[4][32];
  __shared__ int idxt[64];
  __shared__ float sc[64], sh[64], bb[64];
  int t = threadIdx.x;
  int r = t >> 2, q = t & 3;
  {
    const float4* w4 = (const float4*)(w2d + r * 64 + q * 16);
    unsigned wu[8];
#pragma unroll
    for (int uu = 0; uu < 4; uu++) {
      float4 v = w4[uu];
      wu[uu * 2] = pack_bf16x2(v.x, v.y);
      wu[uu * 2 + 1] = pack_bf16x2(v.z, v.w);
    }
    *(uint4*)&WlU[r * 36 + q * 8] = *(uint4*)&wu[0];
    *(uint4*)&WlU[r * 36 + q * 8 + 4] = *(uint4*)&wu[4];
  }
  if (t < 64) {
    float mu = aD[t] / (float)NSAMP;
    float var = aD[64 + t] / (float)NSAMP - mu * mu;
    float scale = dg[t] * rsqrtf(var + EPSf);
    sc[t] = scale;
    sh[t] = dbe[t] - mu * scale;
    bb[t] = b2d[t];
  }
  int wave = t >> 6, lane = t & 63;
  int lr = lane & 15, lg = lane >> 4;
  int p = r >> 4;
  int wblk = blockIdx.x >> 3;  // 0..511
  int bbase = batch * Nn;
#pragma unroll 1
  for (int tt = 0; tt < 4; tt++) {
    int tile = wblk * 4 + tt;
    int ptb = batch * Nn + tile * 4;
    __syncthreads();
    if (t < 64) idxt[t] = idx[ptb * 16 + t];
    if (t < 128)
      Gs[t >> 5][t & 31] =
          *(const unsigned*)(FS + (size_t)(ptb + (t >> 5)) * FT_STRIDE + 128 + (t & 31) * 4);
    __syncthreads();
    const char* orow = FO + (size_t)(bbase + idxt[r]) * FT_STRIDE + 128;
    uint4 g0 = *(const uint4*)(orow + q * 32);
    uint4 g1 = *(const uint4*)(orow + q * 32 + 16);
    unsigned hu[8];
#pragma unroll
    for (int uu = 0; uu < 8; uu++) {
      unsigned gdo2 = (uu < 4) ? ((const unsigned*)&g0)[uu] : ((const unsigned*)&g1)[uu - 4];
      unsigned gds2 = Gs[p][q * 8 + uu];
      int c = q * 16 + uu * 2;
      float h0 = fmaxf(sc[c] * (bf16_lo(gds2) - bf16_lo(gdo2)) + sh[c], 0.f);
      float h1 = fmaxf(sc[c + 1] * (bf16_hi(gds2) - bf16_hi(gdo2)) + sh[c + 1], 0.f);
      hu[uu] = pack_bf16x2(h0, h1);
    }
    *(uint4*)&HtU[r * 36 + q * 8] = *(uint4*)&hu[0];
    *(uint4*)&HtU[r * 36 + q * 8 + 4] = *(uint4*)&hu[4];
    __syncthreads();
    v4f acc4[4] = {{0, 0, 0, 0}, {0, 0, 0, 0}, {0, 0, 0, 0}, {0, 0, 0, 0}};
    v8bf a0 = *(const v8bf*)&HtU[(wave * 16 + lr) * 36 + lg * 4];
    v8bf a1 = *(const v8bf*)&HtU[(wave * 16 + lr) * 36 + 16 + lg * 4];
#pragma unroll
    for (int c = 0; c < 4; c++) {
      v8bf b0 = *(const v8bf*)&WlU[(c * 16 + lr) * 36 + lg * 4];
      v8bf b1 = *(const v8bf*)&WlU[(c * 16 + lr) * 36 + 16 + lg * 4];
      acc4[c] = __builtin_amdgcn_mfma_f32_16x16x32_bf16(a0, b0, acc4[c], 0, 0, 0);
      acc4[c] = __builtin_amdgcn_mfma_f32_16x16x32_bf16(a1, b1, acc4[c], 0, 0, 0);
    }
#pragma unroll
    for (int c = 0; c < 4; c++) {
      float mm = fmaxf(fmaxf(acc4[c][0], acc4[c][1]), fmaxf(acc4[c][2], acc4[c][3]));
      mm = fmaxf(mm, __shfl_xor(mm, 16));
      mm = fmaxf(mm, __shfl_xor(mm, 32));
      if (lane < 16) dout[(size_t)(ptb + wave) * 64 + c * 16 + lane] = mm + bb[c * 16 + lane];
    }
  }
}

// ---- YF(bf16) = [DF | relu_bn(YS)] @ [fw1L | W']^T + fin BN stats (LDS-free) ----
__global__ __launch_bounds__(256) void yfin_gemm(
    const float* __restrict__ DF0, const float* __restrict__ DF1,
    const float* __restrict__ YS0, const float* __restrict__ YS1,
    const unsigned* __restrict__ Wcomb, const float* __restrict__ sg,
    const float* __restrict__ sbe, unsigned* __restrict__ YF0b,
    unsigned* __restrict__ YF1b, float* __restrict__ acc) {
  int dir = blockIdx.y;
  const float* df = dir ? DF1 : DF0;
  const float* ysim = dir ? YS1 : YS0;
  unsigned* yfb = dir ? YF1b : YF0b;
  const float* aS = acc + 256 + dir * 128;
  float* accF = acc + 512 + dir * 256;
  __shared__ float redS[4][128], redQ[4][128];
  __shared__ float scs[64], shs[64];
  int t = threadIdx.x;
  int ptb = blockIdx.x * 64;
  if (t < 64) {
    float mu = aS[t] / (float)NPTS;
    float var = aS[64 + t] / (float)NPTS - mu * mu;
    float scale = sg[t] * rsqrtf(var + EPSf);
    scs[t] = scale;
    shs[t] = sbe[t] - mu * scale;
  }
  __syncthreads();
  int wave = t >> 6, lane = t & 63, lr = lane & 15, lg = lane >> 4;
  int ptB = ptb + wave * 16 + lr;
  v8bf pb[4];
#pragma unroll
  for (int kk = 0; kk < 4; kk++) {
    int ch = kk * 32 + lg * 8;
    float4 v0, v1;
    if (ch < 64) {
      v0 = *(const float4*)(df + (size_t)ptB * 64 + ch);
      v1 = *(const float4*)(df + (size_t)ptB * 64 + ch + 4);
    } else {
      int c2 = ch - 64;
      float4 y0 = *(const float4*)(ysim + (size_t)ptB * 64 + c2);
      float4 y1 = *(const float4*)(ysim + (size_t)ptB * 64 + c2 + 4);
      v0.x = fmaxf(scs[c2] * y0.x + shs[c2], 0.f);
      v0.y = fmaxf(scs[c2 + 1] * y0.y + shs[c2 + 1], 0.f);
      v0.z = fmaxf(scs[c2 + 2] * y0.z + shs[c2 + 2], 0.f);
      v0.w = fmaxf(scs[c2 + 3] * y0.w + shs[c2 + 3], 0.f);
      v1.x = fmaxf(scs[c2 + 4] * y1.x + shs[c2 + 4], 0.f);
      v1.y = fmaxf(scs[c2 + 5] * y1.y + shs[c2 + 5], 0.f);
      v1.z = fmaxf(scs[c2 + 6] * y1.z + shs[c2 + 6], 0.f);
      v1.w = fmaxf(scs[c2 + 7] * y1.w + shs[c2 + 7], 0.f);
    }
    unsigned u4[4] = {pack_bf16x2(v0.x, v0.y), pack_bf16x2(v0.z, v0.w),
                      pack_bf16x2(v1.x, v1.y), pack_bf16x2(v1.z, v1.w)};
    pb[kk] = *(const v8bf*)u4;
  }
#pragma unroll
  for (int jb = 0; jb < 8; jb++) {
    int jrow = jb * 16 + lr;
    v4f a4 = {0, 0, 0, 0};
#pragma unroll
    for (int kk = 0; kk < 4; kk++) {
      v8bf wfrag = *(const v8bf*)(Wcomb + (size_t)jrow * 64 + kk * 16 + lg * 4);
      a4 = __builtin_amdgcn_mfma_f32_16x16x32_bf16(wfrag, pb[kk], a4, 0, 0, 0);
    }
    uint2 pk = make_uint2(pack_bf16x2(a4[0], a4[1]), pack_bf16x2(a4[2], a4[3]));
    *(uint2*)(yfb + (size_t)ptB * 64 + jb * 8 + lg * 2) = pk;
    float s0 = a4[0], s1 = a4[1], s2 = a4[2], s3 = a4[3];
    float q0 = s0 * s0, q1 = s1 * s1, q2 = s2 * s2, q3 = s3 * s3;
#define R4(x)              \
  x += __shfl_xor(x, 1);   \
  x += __shfl_xor(x, 2);   \
  x += __shfl_xor(x, 4);   \
  x += __shfl_xor(x, 8);
    R4(s0) R4(s1) R4(s2) R4(s3) R4(q0) R4(q1) R4(q2) R4(q3)
#undef R4
    if (lr == 0) {
      int j0 = jb * 16 + lg * 4;
      redS[wave][j0] = s0;
      redS[wave][j0 + 1] = s1;
      redS[wave][j0 + 2] = s2;
      redS[wave][j0 + 3] = s3;
      redQ[wave][j0] = q0;
      redQ[wave][j0 + 1] = q1;
      redQ[wave][j0 + 2] = q2;
      redQ[wave][j0 + 3] = q3;
    }
  }
  __syncthreads();
  if (t < 128) {
    atomicAdd(accF + t, redS[0][t] + redS[1][t] + redS[2][t] + redS[3][t]);
    atomicAdd(accF + 128 + t, redQ[0][t] + redQ[1][t] + redQ[2][t] + redQ[3][t]);
  }
}

// ---------------- out = relu(bn(YFb)) @ fw2^T + fb2 (MFMA, bf16 tiles) ------------
__global__ __launch_bounds__(256) void finout_gemm(
    const unsigned* __restrict__ YF0b, const unsigned* __restrict__ YF1b,
    const float* __restrict__ acc, const float* __restrict__ fg,
    const float* __restrict__ fbe, const float* __restrict__ fw2,
    const float* __restrict__ fb2, float* __restrict__ out) {
  int dir = blockIdx.y;
  const unsigned* yfb = dir ? YF1b : YF0b;
  const float* aF = acc + 512 + dir * 256;
  float* outp = out + (size_t)dir * NPTS * 64;
  __shared__ __align__(16) unsigned Au[64 * 68];
  __shared__ __align__(16) unsigned Bu[64 * 68];
  __shared__ float scl[128], shf[128], bb[64];
  int t = threadIdx.x;
  if (t < 128) {
    float mu = aF[t] / (float)NPTS;
    float var = aF[128 + t] / (float)NPTS - mu * mu;
    float scale = fg[t] * rsqrtf(var + EPSf);
    scl[t] = scale;
    shf[t] = fbe[t] - mu * scale;
  }
  if (t < 64) bb[t] = fb2[t];
  int ptb = blockIdx.x * 64;
#pragma unroll
  for (int i = 0; i < 16; i++) {
    int ix = t + i * 256;
    int row = ix >> 6, uc = ix & 63;
    int sw = uc ^ ((row & 7) << 2);
    float2 w = *(const float2*)(fw2 + (size_t)row * 128 + uc * 2);
    Bu[row * 68 + sw] = pack_bf16x2(w.x, w.y);
  }
  __syncthreads();  // scl/shf ready
#pragma unroll
  for (int i = 0; i < 16; i++) {
    int ix = t + i * 256;
    int row = ix >> 6, uc = ix & 63;
    int sw = uc ^ ((row & 7) << 2);
    unsigned uv = yfb[(size_t)(ptb + row) * 64 + uc];
    float h0 = fmaxf(scl[uc * 2] * bf16_lo(uv) + shf[uc * 2], 0.f);
    float h1 = fmaxf(scl[uc * 2 + 1] * bf16_hi(uv) + shf[uc * 2 + 1], 0.f);
    Au[row * 68 + sw] = pack_bf16x2(h0, h1);
  }
  __syncthreads();
  int wave = t >> 6, lane = t & 63, lr = lane & 15, lg = lane >> 4;
  v8bf a[4];
  {
    int arow = wave * 16 + lr;
    int base = arow * 68, sx = (arow & 7) << 2;
#pragma unroll
    for (int kk = 0; kk < 4; kk++)
      a[kk] = *(const v8bf*)&Au[base + ((kk * 16 + lg * 4) ^ sx)];
  }
  v4f acc4[4] = {{0, 0, 0, 0}, {0, 0, 0, 0}, {0, 0, 0, 0}, {0, 0, 0, 0}};
#pragma unroll
  for (int c = 0; c < 4; c++) {
    int brow = c * 16 + lr;
    int base = brow * 68, sx = (brow & 7) << 2;
#pragma unroll
    for (int kk = 0; kk < 4; kk++) {
      v8bf b = *(const v8bf*)&Bu[base + ((kk * 16 + lg * 4) ^ sx)];
      acc4[c] = __builtin_amdgcn_mfma_f32_16x16x32_bf16(a[kk], b, acc4[c], 0, 0, 0);
    }
  }
#pragma unroll
  for (int c = 0; c < 4; c++) {
    float bbv = bb[c * 16 + lr];
#pragma unroll
    for (int i = 0; i < 4; i++)
      outp[(size_t)(ptb + wave * 16 + lg * 4 + i) * 64 + c * 16 + lr] =
          acc4[c][i] + bbv;
  }
}

extern "C" void kernel_launch(void* const* d_in, const int* in_sizes, int n_in,
                              void* d_out, int out_size, void* d_ws, size_t ws_size,
                              hipStream_t stream) {
  const float* f0 = (const float*)d_in[0];
  const float* f1 = (const float*)d_in[1];
  const int* i01 = (const int*)d_in[2];
  const int* i10 = (const int*)d_in[3];
  const float* dw1 = (const float*)d_in[4];
  const float* dg = (const float*)d_in[6];
  const float* dbe = (const float*)d_in[7];
  const float* dw2 = (const float*)d_in[8];
  const float* db2 = (const float*)d_in[9];
  const float* sw1 = (const float*)d_in[10];
  const float* sg = (const float*)d_in[12];
  const float* sbe = (const float*)d_in[13];
  const float* sw2 = (const float*)d_in[14];
  const float* sb2 = (const float*)d_in[15];
  const float* fw1 = (const float*)d_in[16];
  const float* fg = (const float*)d_in[18];
  const float* fbe = (const float*)d_in[19];
  const float* fw2 = (const float*)d_in[20];
  const float* fb2 = (const float*)d_in[21];
  (void)sb2;  // cancels exactly under fin-BN after the W' fold

  char* wsb = (char*)d_ws;
  float* out = (float*)d_out;

  char* FT0 = wsb;                 // 12 MB + pad
  char* FT1 = wsb + FTSZ;          // 12 MB + pad
  float* acc = (float*)(wsb + 2 * FTSZ);              // 1024 floats
  float* Wp = (float*)(wsb + 2 * FTSZ + 16384);       // 128x64 fp32 = 32KB
  unsigned* Wcomb = (unsigned*)(wsb + 2 * FTSZ + 49152);  // 128x64 u32 = 32KB
  float* YS0 = (float*)(wsb + 2 * FTSZ + 131072);
  float* YS1 = YS0 + GSZ;
  float* DF0 = YS1 + GSZ;
  float* DF1 = DF0 + GSZ;
  unsigned* YF0b = (unsigned*)(DF1 + GSZ);        // 8 MB (bf16 YF)
  unsigned* YF1b = YF0b + (size_t)NPTS * 64;      // 8 MB

  wprep<<<32, 256, 0, stream>>>(fw1, sw2, Wp, acc);
  wpack<<<32, 256, 0, stream>>>(fw1, Wp, Wcomb);
  gemmG<<<dim3(512, 1, 2), 256, 0, stream>>>(f0, f1, dw1, sw1, FT0, FT1);

  stats_sim<<<2048, 256, 0, stream>>>(FT0, FT1, i01, i10, YS0, YS1, acc);

  diff_out_k<<<4096, 256, 0, stream>>>(FT0, FT1, i01, i10, dw2, db2, acc, dg, dbe,
                                       DF0, DF1);

  yfin_gemm<<<dim3(512, 2), 256, 0, stream>>>(DF0, DF1, YS0, YS1, Wcomb, sg, sbe,
                                              YF0b, YF1b, acc);

  finout_gemm<<<dim3(512, 2), 256, 0, stream>>>(YF0b, YF1b, acc, fg, fbe, fw2, fb2, out);
}

// Round 26
// 158.033 us; speedup vs baseline: 1.2286x; 1.0069x over previous
//
#include <hip/hip_runtime.h>
#include <hip/hip_fp16.h>

// PointSetDifferenceModule: B=4, N=8192, C=64, K=16
// Round 26: DF and YS stored as bf16 (DF exact — yfin rounded to bf16 on read
// anyway; YS adds one quantization of the same class as existing ones).
// Saves ~24MB of intermediate traffic. Rest = round 25 (159.1us, 0.03125).
// FT row (384B): [ f fp16 x64 | G_d bf16 x64 | G_s bf16 x64 ]

#define Bn 4
#define Nn 8192
#define NPTS (Bn * Nn)        // 32768
#define NSAMP (NPTS * 16)     // 524288
#define EPSf 1e-5f
#define FT_STRIDE 384
#define FTSZ ((size_t)NPTS * FT_STRIDE + 1024)

typedef __attribute__((ext_vector_type(8))) short v8bf;
typedef __attribute__((ext_vector_type(4))) float v4f;
typedef __attribute__((ext_vector_type(2))) _Float16 v2h;

union U2H {
  unsigned u;
  v2h h;
};

__device__ inline unsigned pack_bf16x2(float a, float b) {
  unsigned ua = __float_as_uint(a), ub = __float_as_uint(b);
  ua = (ua + 0x7FFFu + ((ua >> 16) & 1u)) >> 16;
  ub = (ub + 0x7FFFu + ((ub >> 16) & 1u)) >> 16;
  return (ub << 16) | ua;
}
__device__ inline float bf16_lo(unsigned u) { return __uint_as_float(u << 16); }
__device__ inline float bf16_hi(unsigned u) { return __uint_as_float(u & 0xFFFF0000u); }

__device__ inline float dot2acc(unsigned a, unsigned b, float c) {
  U2H ua, ub;
  ua.u = a;
  ub.u = b;
#if __has_builtin(__builtin_amdgcn_fdot2)
  return __builtin_amdgcn_fdot2(ua.h, ub.h, c, false);
#else
  return c + (float)ua.h.x * (float)ub.h.x + (float)ua.h.y * (float)ub.h.y;
#endif
}

// ------ W' = fw1[:,64:128] @ sw2 (128x64 fp32) + acc zeroing (folded memset) ------
__global__ void wprep(const float* __restrict__ fw1, const float* __restrict__ sw2,
                      float* __restrict__ Wp, float* __restrict__ acc) {
  int gid = blockIdx.x * 256 + threadIdx.x;  // 8192
  if (gid < 1024) acc[gid] = 0.f;
  int j = gid >> 6, k = gid & 63;
  float s = 0.f;
#pragma unroll 8
  for (int c = 0; c < 64; c++) s += fw1[j * 128 + 64 + c] * sw2[c * 64 + k];
  Wp[gid] = s;
}

// ---------------- Wcomb[j][u] = pack_bf16( [fw1L | Wp][j][2u..2u+1] ) ------------
__global__ void wpack(const float* __restrict__ fw1, const float* __restrict__ Wp,
                      unsigned* __restrict__ Wcomb) {
  int gid = blockIdx.x * 256 + threadIdx.x;  // 8192
  int j = gid >> 6, u = gid & 63;
  int c = u * 2;
  float a, b;
  if (c < 64) {
    a = fw1[j * 128 + c];
    b = fw1[j * 128 + c + 1];
  } else {
    a = Wp[j * 64 + (c - 64)];
    b = Wp[j * 64 + (c - 64) + 1];
  }
  Wcomb[gid] = pack_bf16x2(a, b);
}

// ---------------- build fused tables: f fp16 + G_d, G_s bf16 ----------------
__global__ __launch_bounds__(256) void gemmG(const float* __restrict__ f0,
                                             const float* __restrict__ f1,
                                             const float* __restrict__ wd,
                                             const float* __restrict__ wsim,
                                             char* __restrict__ FT0,
                                             char* __restrict__ FT1) {
  int z = blockIdx.z;
  const float* F = z ? f1 : f0;
  char* FT = z ? FT1 : FT0;
  __shared__ float Fl[64][65];
  __shared__ float Wd[64][65];
  __shared__ float Ws[64][65];
  int t = threadIdx.x;
#pragma unroll
  for (int i = 0; i < 16; i++) {
    int ix = t + i * 256;
    Wd[ix >> 6][ix & 63] = wd[ix];
    Ws[ix >> 6][ix & 63] = wsim[ix];
  }
  int ptb = blockIdx.x * 64;
#pragma unroll
  for (int i = 0; i < 8; i++) {
    int pr = t + i * 256;  // pair index 0..2047
    int row = pr >> 5, c2 = pr & 31;
    float2 v = *(const float2*)(F + (size_t)(ptb + row) * 64 + c2 * 2);
    Fl[row][c2 * 2] = v.x;
    Fl[row][c2 * 2 + 1] = v.y;
    __half2 h2 = __floats2half2_rn(v.x, v.y);
    *(unsigned*)(FT + (size_t)(ptb + row) * FT_STRIDE + c2 * 4) =
        *reinterpret_cast<unsigned*>(&h2);
  }
  __syncthreads();
  int ty = t >> 4, tx = t & 15, r0 = ty * 4, c0 = tx * 4;
  float ad[4][4] = {}, as_[4][4] = {};
#pragma unroll 4
  for (int j = 0; j < 64; ++j) {
    float a[4], w1[4], w2[4];
#pragma unroll
    for (int i = 0; i < 4; i++) a[i] = Fl[r0 + i][j];
#pragma unroll
    for (int m = 0; m < 4; m++) {
      w1[m] = Wd[c0 + m][j];
      w2[m] = Ws[c0 + m][j];
    }
#pragma unroll
    for (int i = 0; i < 4; i++)
#pragma unroll
      for (int m = 0; m < 4; m++) {
        ad[i][m] += a[i] * w1[m];
        as_[i][m] += a[i] * w2[m];
      }
  }
#pragma unroll
  for (int i = 0; i < 4; i++) {
    char* row = FT + (size_t)(ptb + r0 + i) * FT_STRIDE;
    uint2 gd2 = make_uint2(pack_bf16x2(ad[i][0], ad[i][1]),
                           pack_bf16x2(ad[i][2], ad[i][3]));
    *(uint2*)(row + 128 + c0 * 2) = gd2;
    uint2 gs2 = make_uint2(pack_bf16x2(as_[i][0], as_[i][1]),
                           pack_bf16x2(as_[i][2], as_[i][3]));
    *(uint2*)(row + 256 + c0 * 2) = gs2;
  }
}

// ---------------- diff stats + sim softmax + y_sim (8 points per wave) ----------
// YS stored bf16 (32 u32/point).
__global__ __launch_bounds__(256) void stats_sim(
    const char* __restrict__ FT0, const char* __restrict__ FT1,
    const int* __restrict__ i01, const int* __restrict__ i10,
    unsigned* __restrict__ YS0b, unsigned* __restrict__ YS1b,
    float* __restrict__ acc) {
  int u = blockIdx.x & 7;
  int dir = u & 1, batch = u >> 1;
  const char* FS = dir ? FT1 : FT0;
  const char* FO = dir ? FT0 : FT1;
  const int* idx = dir ? i10 : i01;
  unsigned* ysb = dir ? YS1b : YS0b;
  float* accDiff = acc + dir * 128;
  float* accSim = acc + 256 + dir * 128;
  int lane = threadIdx.x & 63, wave = threadIdx.x >> 6;
  int s = lane & 7, g = lane >> 3;
  int ptbase = batch * Nn + (blockIdx.x >> 3) * 32 + wave * 8;
  int bbase = batch * Nn;
  int myidx0 = idx[ptbase * 16 + lane];
  int myidx1 = idx[ptbase * 16 + 64 + lane];
  const char* srow = FS + (size_t)(ptbase + g) * FT_STRIDE;
  uint4 fs4 = *(const uint4*)(srow + s * 16);
  uint4 gds4 = *(const uint4*)(srow + 128 + s * 16);
  float gds[8] = {bf16_lo(gds4.x), bf16_hi(gds4.x), bf16_lo(gds4.y), bf16_hi(gds4.y),
                  bf16_lo(gds4.z), bf16_hi(gds4.z), bf16_lo(gds4.w), bf16_hi(gds4.w)};
  const char* ob = FO + (size_t)bbase * FT_STRIDE;
  int gq = (g & 3) * 16;
  bool hi = g >= 4;
  float S1[8] = {0, 0, 0, 0, 0, 0, 0, 0};
  float S2[8] = {0, 0, 0, 0, 0, 0, 0, 0};
  float ya[8] = {0, 0, 0, 0, 0, 0, 0, 0};
  float den = 0.f;
#pragma unroll 1
  for (int kc = 0; kc < 16; kc += 4) {
    uint4 fo[4], gdo[4], gso[4];
#pragma unroll
    for (int k = 0; k < 4; k++) {
      int jA = __shfl(myidx0, gq + kc + k);
      int jB = __shfl(myidx1, gq + kc + k);
      int j = hi ? jB : jA;
      const char* orow = ob + (size_t)j * FT_STRIDE;
      fo[k] = *(const uint4*)(orow + s * 16);
      gdo[k] = *(const uint4*)(orow + 128 + s * 16);
      gso[k] = *(const uint4*)(orow + 256 + s * 16);
    }
    float sims[4];
#pragma unroll
    for (int k = 0; k < 4; k++) {
      float p = dot2acc(fs4.x, fo[k].x, 0.f);
      p = dot2acc(fs4.y, fo[k].y, p);
      p = dot2acc(fs4.z, fo[k].z, p);
      p = dot2acc(fs4.w, fo[k].w, p);
      p += __shfl_xor(p, 4);
      p += __shfl_xor(p, 2);
      p += __shfl_xor(p, 1);
      sims[k] = p;
      float t0 = bf16_lo(gdo[k].x), t1 = bf16_hi(gdo[k].x);
      float t2 = bf16_lo(gdo[k].y), t3 = bf16_hi(gdo[k].y);
      float t4 = bf16_lo(gdo[k].z), t5 = bf16_hi(gdo[k].z);
      float t6 = bf16_lo(gdo[k].w), t7 = bf16_hi(gdo[k].w);
      S1[0] += t0; S2[0] += t0 * t0;
      S1[1] += t1; S2[1] += t1 * t1;
      S1[2] += t2; S2[2] += t2 * t2;
      S1[3] += t3; S2[3] += t3 * t3;
      S1[4] += t4; S2[4] += t4 * t4;
      S1[5] += t5; S2[5] += t5 * t5;
      S1[6] += t6; S2[6] += t6 * t6;
      S1[7] += t7; S2[7] += t7 * t7;
    }
#pragma unroll
    for (int k = 0; k < 4; k++) {
      float e = __expf(sims[k]);
      den += e;
      ya[0] += e * bf16_lo(gso[k].x);
      ya[1] += e * bf16_hi(gso[k].x);
      ya[2] += e * bf16_lo(gso[k].y);
      ya[3] += e * bf16_hi(gso[k].y);
      ya[4] += e * bf16_lo(gso[k].z);
      ya[5] += e * bf16_hi(gso[k].z);
      ya[6] += e * bf16_lo(gso[k].w);
      ya[7] += e * bf16_hi(gso[k].w);
    }
  }
  float inv = 1.f / den;
#pragma unroll
  for (int i = 0; i < 8; i++) ya[i] *= inv;
  {
    unsigned yp[4] = {pack_bf16x2(ya[0], ya[1]), pack_bf16x2(ya[2], ya[3]),
                      pack_bf16x2(ya[4], ya[5]), pack_bf16x2(ya[6], ya[7])};
    *(uint4*)(ysb + (size_t)(ptbase + g) * 32 + s * 4) = *(uint4*)yp;
  }
  float sd[8], qd[8], qs[8];
#pragma unroll
  for (int i = 0; i < 8; i++) {
    sd[i] = 16.f * gds[i] - S1[i];
    qd[i] = 16.f * gds[i] * gds[i] - 2.f * gds[i] * S1[i] + S2[i];
    qs[i] = ya[i] * ya[i];
  }
#define GRED(x)           \
  x += __shfl_xor(x, 8);  \
  x += __shfl_xor(x, 16); \
  x += __shfl_xor(x, 32);
#pragma unroll
  for (int i = 0; i < 8; i++) {
    GRED(sd[i]) GRED(qd[i]) GRED(ya[i]) GRED(qs[i])
  }
#undef GRED
  __shared__ float red[4][4][64];
  if (lane < 8) {
#pragma unroll
    for (int i = 0; i < 8; i++) {
      red[wave][0][s * 8 + i] = sd[i];
      red[wave][1][s * 8 + i] = qd[i];
      red[wave][2][s * 8 + i] = ya[i];
      red[wave][3][s * 8 + i] = qs[i];
    }
  }
  __syncthreads();
  if (wave == 0) {
    float v = red[0][0][lane] + red[1][0][lane] + red[2][0][lane] + red[3][0][lane];
    atomicAdd(accDiff + lane, v);
    v = red[0][1][lane] + red[1][1][lane] + red[2][1][lane] + red[3][1][lane];
    atomicAdd(accDiff + 64 + lane, v);
    v = red[0][2][lane] + red[1][2][lane] + red[2][2][lane] + red[3][2][lane];
    atomicAdd(accSim + lane, v);
    v = red[0][3][lane] + red[1][3][lane] + red[2][3][lane] + red[3][3][lane];
    atomicAdd(accSim + 64 + lane, v);
  }
}

// ---------------- diff output: gather bf16 + BN/relu + MFMA GEMM + max over K --------
// DF stored bf16 (32 u32/point) — exact (yfin rounded to bf16 on read anyway).
__global__ __launch_bounds__(256) void diff_out_k(
    const char* __restrict__ FT0, const char* __restrict__ FT1,
    const int* __restrict__ i01, const int* __restrict__ i10,
    const float* __restrict__ w2d, const float* __restrict__ b2d,
    const float* __restrict__ acc, const float* __restrict__ dg,
    const float* __restrict__ dbe, unsigned* __restrict__ DF0b,
    unsigned* __restrict__ DF1b) {
  int u = blockIdx.x & 7;
  int dir = u & 1, batch = u >> 1;
  const char* FS = dir ? FT1 : FT0;
  const char* FO = dir ? FT0 : FT1;
  const int* idx = dir ? i10 : i01;
  const float* aD = acc + dir * 128;
  unsigned* doutb = dir ? DF1b : DF0b;
  __shared__ __align__(16) unsigned WlU[64 * 36];
  __shared__ __align__(16) unsigned HtU[64 * 36];
  __shared__ unsigned Gs[4][32];
  __shared__ int idxt[64];
  __shared__ float sc[64], sh[64], bb[64];
  int t = threadIdx.x;
  int r = t >> 2, q = t & 3;
  {
    const float4* w4 = (const float4*)(w2d + r * 64 + q * 16);
    unsigned wu[8];
#pragma unroll
    for (int uu = 0; uu < 4; uu++) {
      float4 v = w4[uu];
      wu[uu * 2] = pack_bf16x2(v.x, v.y);
      wu[uu * 2 + 1] = pack_bf16x2(v.z, v.w);
    }
    *(uint4*)&WlU[r * 36 + q * 8] = *(uint4*)&wu[0];
    *(uint4*)&WlU[r * 36 + q * 8 + 4] = *(uint4*)&wu[4];
  }
  if (t < 64) {
    float mu = aD[t] / (float)NSAMP;
    float var = aD[64 + t] / (float)NSAMP - mu * mu;
    float scale = dg[t] * rsqrtf(var + EPSf);
    sc[t] = scale;
    sh[t] = dbe[t] - mu * scale;
    bb[t] = b2d[t];
  }
  int wave = t >> 6, lane = t & 63;
  int lr = lane & 15, lg = lane >> 4;
  int p = r >> 4;
  int wblk = blockIdx.x >> 3;  // 0..511
  int bbase = batch * Nn;
#pragma unroll 1
  for (int tt = 0; tt < 4; tt++) {
    int tile = wblk * 4 + tt;
    int ptb = batch * Nn + tile * 4;
    __syncthreads();
    if (t < 64) idxt[t] = idx[ptb * 16 + t];
    if (t < 128)
      Gs[t >> 5][t & 31] =
          *(const unsigned*)(FS + (size_t)(ptb + (t >> 5)) * FT_STRIDE + 128 + (t & 31) * 4);
    __syncthreads();
    const char* orow = FO + (size_t)(bbase + idxt[r]) * FT_STRIDE + 128;
    uint4 g0 = *(const uint4*)(orow + q * 32);
    uint4 g1 = *(const uint4*)(orow + q * 32 + 16);
    unsigned hu[8];
#pragma unroll
    for (int uu = 0; uu < 8; uu++) {
      unsigned gdo2 = (uu < 4) ? ((const unsigned*)&g0)[uu] : ((const unsigned*)&g1)[uu - 4];
      unsigned gds2 = Gs[p][q * 8 + uu];
      int c = q * 16 + uu * 2;
      float h0 = fmaxf(sc[c] * (bf16_lo(gds2) - bf16_lo(gdo2)) + sh[c], 0.f);
      float h1 = fmaxf(sc[c + 1] * (bf16_hi(gds2) - bf16_hi(gdo2)) + sh[c + 1], 0.f);
      hu[uu] = pack_bf16x2(h0, h1);
    }
    *(uint4*)&HtU[r * 36 + q * 8] = *(uint4*)&hu[0];
    *(uint4*)&HtU[r * 36 + q * 8 + 4] = *(uint4*)&hu[4];
    __syncthreads();
    v4f acc4[4] = {{0, 0, 0, 0}, {0, 0, 0, 0}, {0, 0, 0, 0}, {0, 0, 0, 0}};
    v8bf a0 = *(const v8bf*)&HtU[(wave * 16 + lr) * 36 + lg * 4];
    v8bf a1 = *(const v8bf*)&HtU[(wave * 16 + lr) * 36 + 16 + lg * 4];
#pragma unroll
    for (int c = 0; c < 4; c++) {
      v8bf b0 = *(const v8bf*)&WlU[(c * 16 + lr) * 36 + lg * 4];
      v8bf b1 = *(const v8bf*)&WlU[(c * 16 + lr) * 36 + 16 + lg * 4];
      acc4[c] = __builtin_amdgcn_mfma_f32_16x16x32_bf16(a0, b0, acc4[c], 0, 0, 0);
      acc4[c] = __builtin_amdgcn_mfma_f32_16x16x32_bf16(a1, b1, acc4[c], 0, 0, 0);
    }
#pragma unroll
    for (int c = 0; c < 4; c++) {
      float mm = fmaxf(fmaxf(acc4[c][0], acc4[c][1]), fmaxf(acc4[c][2], acc4[c][3]));
      mm = fmaxf(mm, __shfl_xor(mm, 16));
      mm = fmaxf(mm, __shfl_xor(mm, 32));
      float v = mm + bb[c * 16 + (lane & 15)];
      float vhi = __shfl_xor(v, 1);  // even lane: channel+1's value
      if (lane < 16 && (lane & 1) == 0)
        doutb[(size_t)(ptb + wave) * 32 + c * 8 + (lane >> 1)] = pack_bf16x2(v, vhi);
    }
  }
}

// ---- YF(bf16) = [DFb | relu_bn(YSb)] @ [fw1L | W']^T + fin BN stats (LDS-free) ----
__global__ __launch_bounds__(256) void yfin_gemm(
    const unsigned* __restrict__ DF0b, const unsigned* __restrict__ DF1b,
    const unsigned* __restrict__ YS0b, const unsigned* __restrict__ YS1b,
    const unsigned* __restrict__ Wcomb, const float* __restrict__ sg,
    const float* __restrict__ sbe, unsigned* __restrict__ YF0b,
    unsigned* __restrict__ YF1b, float* __restrict__ acc) {
  int dir = blockIdx.y;
  const unsigned* dfb = dir ? DF1b : DF0b;
  const unsigned* ysb = dir ? YS1b : YS0b;
  unsigned* yfb = dir ? YF1b : YF0b;
  const float* aS = acc + 256 + dir * 128;
  float* accF = acc + 512 + dir * 256;
  __shared__ float redS[4][128], redQ[4][128];
  __shared__ float scs[64], shs[64];
  int t = threadIdx.x;
  int ptb = blockIdx.x * 64;
  if (t < 64) {
    float mu = aS[t] / (float)NPTS;
    float var = aS[64 + t] / (float)NPTS - mu * mu;
    float scale = sg[t] * rsqrtf(var + EPSf);
    scs[t] = scale;
    shs[t] = sbe[t] - mu * scale;
  }
  __syncthreads();
  int wave = t >> 6, lane = t & 63, lr = lane & 15, lg = lane >> 4;
  int ptB = ptb + wave * 16 + lr;
  v8bf pb[4];
#pragma unroll
  for (int kk = 0; kk < 2; kk++) {
    // DF half: already bf16 — direct fragment load
    uint4 d4 = *(const uint4*)(dfb + (size_t)ptB * 32 + kk * 16 + lg * 4);
    pb[kk] = *(const v8bf*)&d4;
  }
#pragma unroll
  for (int kk = 2; kk < 4; kk++) {
    int c2 = (kk - 2) * 32 + lg * 8;  // channel base within YS (0..63)
    uint4 y4 = *(const uint4*)(ysb + (size_t)ptB * 32 + (kk - 2) * 16 + lg * 4);
    const unsigned* yp = (const unsigned*)&y4;
    unsigned u4[4];
#pragma unroll
    for (int w = 0; w < 4; w++) {
      int cc = c2 + w * 2;
      float h0 = fmaxf(scs[cc] * bf16_lo(yp[w]) + shs[cc], 0.f);
      float h1 = fmaxf(scs[cc + 1] * bf16_hi(yp[w]) + shs[cc + 1], 0.f);
      u4[w] = pack_bf16x2(h0, h1);
    }
    pb[kk] = *(const v8bf*)u4;
  }
#pragma unroll
  for (int jb = 0; jb < 8; jb++) {
    int jrow = jb * 16 + lr;
    v4f a4 = {0, 0, 0, 0};
#pragma unroll
    for (int kk = 0; kk < 4; kk++) {
      v8bf wfrag = *(const v8bf*)(Wcomb + (size_t)jrow * 64 + kk * 16 + lg * 4);
      a4 = __builtin_amdgcn_mfma_f32_16x16x32_bf16(wfrag, pb[kk], a4, 0, 0, 0);
    }
    uint2 pk = make_uint2(pack_bf16x2(a4[0], a4[1]), pack_bf16x2(a4[2], a4[3]));
    *(uint2*)(yfb + (size_t)ptB * 64 + jb * 8 + lg * 2) = pk;
    float s0 = a4[0], s1 = a4[1], s2 = a4[2], s3 = a4[3];
    float q0 = s0 * s0, q1 = s1 * s1, q2 = s2 * s2, q3 = s3 * s3;
#define R4(x)              \
  x += __shfl_xor(x, 1);   \
  x += __shfl_xor(x, 2);   \
  x += __shfl_xor(x, 4);   \
  x += __shfl_xor(x, 8);
    R4(s0) R4(s1) R4(s2) R4(s3) R4(q0) R4(q1) R4(q2) R4(q3)
#undef R4
    if (lr == 0) {
      int j0 = jb * 16 + lg * 4;
      redS[wave][j0] = s0;
      redS[wave][j0 + 1] = s1;
      redS[wave][j0 + 2] = s2;
      redS[wave][j0 + 3] = s3;
      redQ[wave][j0] = q0;
      redQ[wave][j0 + 1] = q1;
      redQ[wave][j0 + 2] = q2;
      redQ[wave][j0 + 3] = q3;
    }
  }
  __syncthreads();
  if (t < 128) {
    atomicAdd(accF + t, redS[0][t] + redS[1][t] + redS[2][t] + redS[3][t]);
    atomicAdd(accF + 128 + t, redQ[0][t] + redQ[1][t] + redQ[2][t] + redQ[3][t]);
  }
}

// ---------------- out = relu(bn(YFb)) @ fw2^T + fb2 (MFMA, bf16 tiles) ------------
__global__ __launch_bounds__(256) void finout_gemm(
    const unsigned* __restrict__ YF0b, const unsigned* __restrict__ YF1b,
    const float* __restrict__ acc, const float* __restrict__ fg,
    const float* __restrict__ fbe, const float* __restrict__ fw2,
    const float* __restrict__ fb2, float* __restrict__ out) {
  int dir = blockIdx.y;
  const unsigned* yfb = dir ? YF1b : YF0b;
  const float* aF = acc + 512 + dir * 256;
  float* outp = out + (size_t)dir * NPTS * 64;
  __shared__ __align__(16) unsigned Au[64 * 68];
  __shared__ __align__(16) unsigned Bu[64 * 68];
  __shared__ float scl[128], shf[128], bb[64];
  int t = threadIdx.x;
  if (t < 128) {
    float mu = aF[t] / (float)NPTS;
    float var = aF[128 + t] / (float)NPTS - mu * mu;
    float scale = fg[t] * rsqrtf(var + EPSf);
    scl[t] = scale;
    shf[t] = fbe[t] - mu * scale;
  }
  if (t < 64) bb[t] = fb2[t];
  int ptb = blockIdx.x * 64;
#pragma unroll
  for (int i = 0; i < 16; i++) {
    int ix = t + i * 256;
    int row = ix >> 6, uc = ix & 63;
    int sw = uc ^ ((row & 7) << 2);
    float2 w = *(const float2*)(fw2 + (size_t)row * 128 + uc * 2);
    Bu[row * 68 + sw] = pack_bf16x2(w.x, w.y);
  }
  __syncthreads();  // scl/shf ready
#pragma unroll
  for (int i = 0; i < 16; i++) {
    int ix = t + i * 256;
    int row = ix >> 6, uc = ix & 63;
    int sw = uc ^ ((row & 7) << 2);
    unsigned uv = yfb[(size_t)(ptb + row) * 64 + uc];
    float h0 = fmaxf(scl[uc * 2] * bf16_lo(uv) + shf[uc * 2], 0.f);
    float h1 = fmaxf(scl[uc * 2 + 1] * bf16_hi(uv) + shf[uc * 2 + 1], 0.f);
    Au[row * 68 + sw] = pack_bf16x2(h0, h1);
  }
  __syncthreads();
  int wave = t >> 6, lane = t & 63, lr = lane & 15, lg = lane >> 4;
  v8bf a[4];
  {
    int arow = wave * 16 + lr;
    int base = arow * 68, sx = (arow & 7) << 2;
#pragma unroll
    for (int kk = 0; kk < 4; kk++)
      a[kk] = *(const v8bf*)&Au[base + ((kk * 16 + lg * 4) ^ sx)];
  }
  v4f acc4[4] = {{0, 0, 0, 0}, {0, 0, 0, 0}, {0, 0, 0, 0}, {0, 0, 0, 0}};
#pragma unroll
  for (int c = 0; c < 4; c++) {
    int brow = c * 16 + lr;
    int base = brow * 68, sx = (brow & 7) << 2;
#pragma unroll
    for (int kk = 0; kk < 4; kk++) {
      v8bf b = *(const v8bf*)&Bu[base + ((kk * 16 + lg * 4) ^ sx)];
      acc4[c] = __builtin_amdgcn_mfma_f32_16x16x32_bf16(a[kk], b, acc4[c], 0, 0, 0);
    }
  }
#pragma unroll
  for (int c = 0; c < 4; c++) {
    float bbv = bb[c * 16 + lr];
#pragma unroll
    for (int i = 0; i < 4; i++)
      outp[(size_t)(ptb + wave * 16 + lg * 4 + i) * 64 + c * 16 + lr] =
          acc4[c][i] + bbv;
  }
}

extern "C" void kernel_launch(void* const* d_in, const int* in_sizes, int n_in,
                              void* d_out, int out_size, void* d_ws, size_t ws_size,
                              hipStream_t stream) {
  const float* f0 = (const float*)d_in[0];
  const float* f1 = (const float*)d_in[1];
  const int* i01 = (const int*)d_in[2];
  const int* i10 = (const int*)d_in[3];
  const float* dw1 = (const float*)d_in[4];
  const float* dg = (const float*)d_in[6];
  const float* dbe = (const float*)d_in[7];
  const float* dw2 = (const float*)d_in[8];
  const float* db2 = (const float*)d_in[9];
  const float* sw1 = (const float*)d_in[10];
  const float* sg = (const float*)d_in[12];
  const float* sbe = (const float*)d_in[13];
  const float* sw2 = (const float*)d_in[14];
  const float* sb2 = (const float*)d_in[15];
  const float* fw1 = (const float*)d_in[16];
  const float* fg = (const float*)d_in[18];
  const float* fbe = (const float*)d_in[19];
  const float* fw2 = (const float*)d_in[20];
  const float* fb2 = (const float*)d_in[21];
  (void)sb2;  // cancels exactly under fin-BN after the W' fold

  char* wsb = (char*)d_ws;
  float* out = (float*)d_out;

  char* FT0 = wsb;                 // 12 MB + pad
  char* FT1 = wsb + FTSZ;          // 12 MB + pad
  float* acc = (float*)(wsb + 2 * FTSZ);              // 1024 floats
  float* Wp = (float*)(wsb + 2 * FTSZ + 16384);       // 128x64 fp32 = 32KB
  unsigned* Wcomb = (unsigned*)(wsb + 2 * FTSZ + 49152);  // 128x64 u32 = 32KB
  unsigned* YS0b = (unsigned*)(wsb + 2 * FTSZ + 131072);  // 4 MB (bf16 YS)
  unsigned* YS1b = YS0b + (size_t)NPTS * 32;              // 4 MB
  unsigned* DF0b = YS1b + (size_t)NPTS * 32;              // 4 MB (bf16 DF)
  unsigned* DF1b = DF0b + (size_t)NPTS * 32;              // 4 MB
  unsigned* YF0b = DF1b + (size_t)NPTS * 32;              // 8 MB (bf16 YF)
  unsigned* YF1b = YF0b + (size_t)NPTS * 64;              // 8 MB

  wprep<<<32, 256, 0, stream>>>(fw1, sw2, Wp, acc);
  wpack<<<32, 256, 0, stream>>>(fw1, Wp, Wcomb);
  gemmG<<<dim3(512, 1, 2), 256, 0, stream>>>(f0, f1, dw1, sw1, FT0, FT1);

  stats_sim<<<2048, 256, 0, stream>>>(FT0, FT1, i01, i10, YS0b, YS1b, acc);

  diff_out_k<<<4096, 256, 0, stream>>>(FT0, FT1, i01, i10, dw2, db2, acc, dg, dbe,
                                       DF0b, DF1b);

  yfin_gemm<<<dim3(512, 2), 256, 0, stream>>>(DF0b, DF1b, YS0b, YS1b, Wcomb, sg, sbe,
                                              YF0b, YF1b, acc);

  finout_gemm<<<dim3(512, 2), 256, 0, stream>>>(YF0b, YF1b, acc, fg, fbe, fw2, fb2, out);
}